// Round 10
// baseline (538.788 us; speedup 1.0000x reference)
//
#include <hip/hip_runtime.h>
#include <hip/hip_cooperative_groups.h>
#include <hip/hip_bf16.h>
#include <math.h>

namespace cg = cooperative_groups;

#define N_NODES 8192
#define N_EDGES 16384
#define N_E3    1024
#define NGRAPH  256
#define NPG     32
#define SLOPE   (11.0f/48.0f)
#define BN_EPS  1e-5f

__device__ __forceinline__ float rrelu(float v){ return v >= 0.f ? v : SLOPE*v; }
__device__ __forceinline__ float sigm(float v){ return 1.f/(1.f+__expf(-v)); }

typedef _Float16 f16;
typedef __attribute__((ext_vector_type(8))) _Float16 half8v;
typedef __attribute__((ext_vector_type(4))) float f32x4;

struct P {
  const float *x, *eattr, *ea3;
  const int *ei, *ei3;
  const float *bnx_g, *bnx_b, *Wn, *bnode, *We, *be;
  const float *Wnn1, *bias1, *Wih1, *Whh1, *bih1, *bhh1;
  const float *bnc_g, *bnc_b, *Wc1, *bc1, *Wc2, *bc2;
  const float *Wnn2, *bias2, *Wih2, *Whh2, *bih2, *bhh2;
  const float *Ws_ih, *Ws_hh;
  float *mean, *var, *ea12, *nodeA, *nodeA2, *sA1, *sA2, *sB1, *sB2;
  float *cnt1, *cnt2, *nodeB, *nodeB2, *bns1, *bns2, *Wfold;
  f16 *Wz1h, *Wih1h, *Whh1h, *Wc1Th, *Wc2Th, *W2fh, *Wih2h, *Whh2h;
};

__device__ __forceinline__ void zero_block(int zb, float* zptr, int zcount) {
  float4 z4 = make_float4(0.f,0.f,0.f,0.f);
  for (int i = zb*512 + (int)threadIdx.x; i*4 < zcount; i += 16*512)
    ((float4*)zptr)[i] = z4;
}

// ---- conv1: 8 waves x 16 edges; blk < 128 ----
__device__ void conv1f_body(const float* __restrict__ nodeA, const int* __restrict__ ei,
    const float* __restrict__ ea, const f16* __restrict__ Wz1h, float* __restrict__ sbuf,
    int blk, int lane, int wv) {
  int e0 = blk*128 + wv*16;
  int eA = e0 + (lane & 15);
  int src = ei[eA];
  int kb0 = (lane >> 4) * 8;
  const float* ap = nodeA + (size_t)src*64 + kb0;
  float4 v0 = *(const float4*)ap,      v1 = *(const float4*)(ap+4);
  float4 v2 = *(const float4*)(ap+32), v3 = *(const float4*)(ap+36);
  half8v a0, a1;
  a0[0]=(f16)v0.x; a0[1]=(f16)v0.y; a0[2]=(f16)v0.z; a0[3]=(f16)v0.w;
  a0[4]=(f16)v1.x; a0[5]=(f16)v1.y; a0[6]=(f16)v1.z; a0[7]=(f16)v1.w;
  a1[0]=(f16)v2.x; a1[1]=(f16)v2.y; a1[2]=(f16)v2.z; a1[3]=(f16)v2.w;
  a1[4]=(f16)v3.x; a1[5]=(f16)v3.y; a1[6]=(f16)v3.z; a1[7]=(f16)v3.w;
  float eav[12];
  #pragma unroll
  for (int kg = 0; kg < 12; kg++) eav[kg] = ea[eA*12 + kg];
  f32x4 acc[4] = {{0,0,0,0},{0,0,0,0},{0,0,0,0},{0,0,0,0}};
  #pragma unroll
  for (int kg = 0; kg < 12; kg++) {
    f16 s = (f16)eav[kg];
    half8v s0, s1;
    #pragma unroll
    for (int u = 0; u < 8; u++) { s0[u] = a0[u]*s; s1[u] = a1[u]*s; }
    #pragma unroll
    for (int jf = 0; jf < 4; jf++) {
      const f16* wp = Wz1h + (size_t)(kg*64 + jf*16 + (lane & 15))*64 + kb0;
      acc[jf] = __builtin_amdgcn_mfma_f32_16x16x32_f16(s0, *(const half8v*)wp, acc[jf], 0, 0, 0);
      acc[jf] = __builtin_amdgcn_mfma_f32_16x16x32_f16(s1, *(const half8v*)(wp+32), acc[jf], 0, 0, 0);
    }
  }
  int dstv[4];
  #pragma unroll
  for (int r = 0; r < 4; r++) dstv[r] = ei[N_EDGES + e0 + ((lane>>4)<<2) + r];
  #pragma unroll
  for (int jf = 0; jf < 4; jf++) {
    int col = jf*16 + (lane & 15);
    #pragma unroll
    for (int r = 0; r < 4; r++)
      atomicAdd(&sbuf[dstv[r]*64 + col], acc[jf][r]);
  }
}

// ---- conv2: all 256 blocks x 512 thr (eg = blk>>1, qh = blk&1; wave: kgh, jp) ----
__device__ void conv2f_body(const float* __restrict__ nodeB, const int* __restrict__ ei3,
    const float* __restrict__ ea3, const f16* __restrict__ W2fh, float* __restrict__ sbuf,
    int blk, int lane, int wv) {
  int eg = blk >> 1, qh = blk & 1;
  int kgh = wv >> 2, jp = wv & 3;
  int e0 = eg * 16;
  int eA = e0 + (lane & 15);
  int src = ei3[eA];
  int kb0 = qh*64 + (lane >> 4) * 8;
  const float* ap = nodeB + (size_t)src*128 + kb0;
  half8v a0, a1;
  {
    float4 w0 = *(const float4*)ap,        w1 = *(const float4*)(ap+4);
    float4 w2 = *(const float4*)(ap + 32), w3 = *(const float4*)(ap+36);
    a0[0]=(f16)w0.x; a0[1]=(f16)w0.y; a0[2]=(f16)w0.z; a0[3]=(f16)w0.w;
    a0[4]=(f16)w1.x; a0[5]=(f16)w1.y; a0[6]=(f16)w1.z; a0[7]=(f16)w1.w;
    a1[0]=(f16)w2.x; a1[1]=(f16)w2.y; a1[2]=(f16)w2.z; a1[3]=(f16)w2.w;
    a1[4]=(f16)w3.x; a1[5]=(f16)w3.y; a1[6]=(f16)w3.z; a1[7]=(f16)w3.w;
  }
  int eb = eA & (N_E3 - 1);
  float eav[4];
  #pragma unroll
  for (int kk = 0; kk < 4; kk++) eav[kk] = ea3[eb*8 + kgh*4 + kk];
  f32x4 acc[2] = {{0,0,0,0},{0,0,0,0}};
  #pragma unroll
  for (int kk = 0; kk < 4; kk++) {
    f16 s = (f16)eav[kk];
    half8v s0, s1;
    #pragma unroll
    for (int u = 0; u < 8; u++) { s0[u] = a0[u]*s; s1[u] = a1[u]*s; }
    int kg = kgh*4 + kk;
    #pragma unroll
    for (int jj = 0; jj < 2; jj++) {
      int jf = jp*2 + jj;
      const f16* wp = W2fh + (size_t)(kg*128 + jf*16 + (lane & 15))*128 + kb0;
      acc[jj] = __builtin_amdgcn_mfma_f32_16x16x32_f16(s0, *(const half8v*)wp, acc[jj], 0, 0, 0);
      acc[jj] = __builtin_amdgcn_mfma_f32_16x16x32_f16(s1, *(const half8v*)(wp+32), acc[jj], 0, 0, 0);
    }
  }
  int dstv[4];
  #pragma unroll
  for (int r = 0; r < 4; r++) dstv[r] = ei3[(e0 + ((lane>>4)<<2) + r + N_E3) & (2*N_E3 - 1)];
  #pragma unroll
  for (int jj = 0; jj < 2; jj++) {
    int col = (jp*2+jj)*16 + (lane & 15);
    #pragma unroll
    for (int r = 0; r < 4; r++)
      atomicAdd(&sbuf[dstv[r]*128 + col], acc[jj][r]);
  }
}

// ---- fused GRU: 8 waves, rows = blk*128 + wv*16; blk < 64*jt ----
template<int LOGH, int STATS>
__device__ void gruf_body(const float* __restrict__ sbuf, const float* __restrict__ cnt,
    const float* __restrict__ mbias,
    const f16* __restrict__ Wih, const f16* __restrict__ Whh,
    const float* __restrict__ bih, const float* __restrict__ bhh,
    const float* __restrict__ hold, float* __restrict__ hnew,
    float* __restrict__ bns1, float* __restrict__ bns2,
    int blk, int lane, int wv) {
  const int H = 1 << LOGH;
  const int K = H;
  const int jt = H >> 6;
  int bm = blk / jt, bj = blk % jt;
  int n0 = bm * 128 + wv * 16;
  int j0 = bj << 6;
  int row = n0 + (lane & 15);
  int kb0 = (lane >> 4) * 8;

  f32x4 aR[4]  = {{0,0,0,0},{0,0,0,0},{0,0,0,0},{0,0,0,0}};
  f32x4 aZ[4]  = {{0,0,0,0},{0,0,0,0},{0,0,0,0},{0,0,0,0}};
  f32x4 aIN[4] = {{0,0,0,0},{0,0,0,0},{0,0,0,0},{0,0,0,0}};
  f32x4 aHN[4] = {{0,0,0,0},{0,0,0,0},{0,0,0,0},{0,0,0,0}};

  float dn = 1.f / fmaxf(cnt[row], 1.0f);
  for (int k0 = 0; k0 < K; k0 += 32) {
    int kb = k0 + kb0;
    const float* ap = sbuf + (size_t)row * K + kb;
    float4 v0 = *(const float4*)ap, v1 = *(const float4*)(ap + 4);
    float4 b0 = *(const float4*)(mbias + kb), b1 = *(const float4*)(mbias + kb + 4);
    half8v af;
    af[0]=(f16)rrelu(v0.x*dn+b0.x); af[1]=(f16)rrelu(v0.y*dn+b0.y);
    af[2]=(f16)rrelu(v0.z*dn+b0.z); af[3]=(f16)rrelu(v0.w*dn+b0.w);
    af[4]=(f16)rrelu(v1.x*dn+b1.x); af[5]=(f16)rrelu(v1.y*dn+b1.y);
    af[6]=(f16)rrelu(v1.z*dn+b1.z); af[7]=(f16)rrelu(v1.w*dn+b1.w);
    #pragma unroll
    for (int jf = 0; jf < 4; jf++) {
      int wr = j0 + jf*16 + (lane & 15);
      half8v wR = *(const half8v*)(Wih + (size_t)wr*K + kb);
      half8v wZ = *(const half8v*)(Wih + (size_t)(H + wr)*K + kb);
      half8v wN = *(const half8v*)(Wih + (size_t)(2*H + wr)*K + kb);
      aR[jf]  = __builtin_amdgcn_mfma_f32_16x16x32_f16(af, wR, aR[jf], 0, 0, 0);
      aZ[jf]  = __builtin_amdgcn_mfma_f32_16x16x32_f16(af, wZ, aZ[jf], 0, 0, 0);
      aIN[jf] = __builtin_amdgcn_mfma_f32_16x16x32_f16(af, wN, aIN[jf], 0, 0, 0);
    }
  }
  for (int k0 = 0; k0 < K; k0 += 32) {
    int kb = k0 + kb0;
    const float* ap = hold + (size_t)row * K + kb;
    float4 v0 = *(const float4*)ap, v1 = *(const float4*)(ap + 4);
    half8v af;
    af[0]=(f16)v0.x; af[1]=(f16)v0.y; af[2]=(f16)v0.z; af[3]=(f16)v0.w;
    af[4]=(f16)v1.x; af[5]=(f16)v1.y; af[6]=(f16)v1.z; af[7]=(f16)v1.w;
    #pragma unroll
    for (int jf = 0; jf < 4; jf++) {
      int wr = j0 + jf*16 + (lane & 15);
      half8v wR = *(const half8v*)(Whh + (size_t)wr*K + kb);
      half8v wZ = *(const half8v*)(Whh + (size_t)(H + wr)*K + kb);
      half8v wN = *(const half8v*)(Whh + (size_t)(2*H + wr)*K + kb);
      aR[jf]  = __builtin_amdgcn_mfma_f32_16x16x32_f16(af, wR, aR[jf], 0, 0, 0);
      aZ[jf]  = __builtin_amdgcn_mfma_f32_16x16x32_f16(af, wZ, aZ[jf], 0, 0, 0);
      aHN[jf] = __builtin_amdgcn_mfma_f32_16x16x32_f16(af, wN, aHN[jf], 0, 0, 0);
    }
  }
  int r0 = n0 + ((lane >> 4) << 2);
  #pragma unroll
  for (int jf = 0; jf < 4; jf++) {
    int col = j0 + jf*16 + (lane & 15);
    float bR = bih[col] + bhh[col];
    float bZ = bih[H + col] + bhh[H + col];
    float bI = bih[2*H + col], bH = bhh[2*H + col];
    float ssum = 0.f, sq = 0.f;
    #pragma unroll
    for (int r = 0; r < 4; r++) {
      float rr = sigm(aR[jf][r] + bR);
      float zz = sigm(aZ[jf][r] + bZ);
      float nn = tanhf(aIN[jf][r] + bI + rr*(aHN[jf][r] + bH));
      float ho = hold[(size_t)(r0 + r)*H + col];
      float hv = (1.f - zz)*nn + zz*ho;
      hnew[(size_t)(r0 + r)*H + col] = hv;
      if (STATS) { ssum += hv; sq += hv*hv; }
    }
    if (STATS) {
      ssum += __shfl_xor(ssum, 16); ssum += __shfl_xor(ssum, 32);
      sq   += __shfl_xor(sq, 16);   sq   += __shfl_xor(sq, 32);
      if (lane < 16) { atomicAdd(&bns1[col], ssum); atomicAdd(&bns2[col], sq); }
    }
  }
}

// ---- fused FC1+FC2: 8 waves x 16 rows; blk < 64 ----
__device__ void fcf_body(const float* __restrict__ A,
    const f16* __restrict__ W1, const float* __restrict__ b1v,
    const f16* __restrict__ W2, const float* __restrict__ b2v,
    const float* __restrict__ bns1, const float* __restrict__ bns2,
    const float* __restrict__ g, const float* __restrict__ b,
    float* __restrict__ outB, int blk, int lane, int wv) {
  __shared__ f16 y1s[8][16][128];
  int n0 = blk*128 + wv*16;
  int row = n0 + (lane & 15);
  int kb0 = (lane >> 4) * 8;
  const float invN = 1.f / (float)N_NODES;

  const float* ap = A + (size_t)row*64 + kb0;
  half8v af0, af1;
  #pragma unroll
  for (int u = 0; u < 8; u++) {
    int k0i = kb0 + u, k1i = 32 + kb0 + u;
    float m0 = bns1[k0i]*invN, m1 = bns1[k1i]*invN;
    float va0 = bns2[k0i]*invN - m0*m0, va1 = bns2[k1i]*invN - m1*m1;
    af0[u] = (f16)((ap[u]    - m0)*rsqrtf(va0+BN_EPS)*g[k0i] + b[k0i]);
    af1[u] = (f16)((ap[32+u] - m1)*rsqrtf(va1+BN_EPS)*g[k1i] + b[k1i]);
  }
  f32x4 acc1[8] = {{0,0,0,0},{0,0,0,0},{0,0,0,0},{0,0,0,0},
                   {0,0,0,0},{0,0,0,0},{0,0,0,0},{0,0,0,0}};
  #pragma unroll
  for (int jf = 0; jf < 8; jf++) {
    const f16* wp = W1 + (size_t)(jf*16 + (lane & 15))*64 + kb0;
    acc1[jf] = __builtin_amdgcn_mfma_f32_16x16x32_f16(af0, *(const half8v*)wp, acc1[jf], 0, 0, 0);
    acc1[jf] = __builtin_amdgcn_mfma_f32_16x16x32_f16(af1, *(const half8v*)(wp+32), acc1[jf], 0, 0, 0);
  }
  #pragma unroll
  for (int jf = 0; jf < 8; jf++) {
    int col = jf*16 + (lane & 15);
    float bv = b1v[col];
    #pragma unroll
    for (int r = 0; r < 4; r++) {
      int rl = ((lane >> 4) << 2) + r;
      y1s[wv][rl][col] = (f16)rrelu(acc1[jf][r] + bv);
    }
  }
  __syncthreads();
  half8v bf[4];
  #pragma unroll
  for (int q = 0; q < 4; q++)
    bf[q] = *(const half8v*)&y1s[wv][lane & 15][q*32 + kb0];
  f32x4 acc2[8] = {{0,0,0,0},{0,0,0,0},{0,0,0,0},{0,0,0,0},
                   {0,0,0,0},{0,0,0,0},{0,0,0,0},{0,0,0,0}};
  #pragma unroll
  for (int jf = 0; jf < 8; jf++) {
    const f16* wp = W2 + (size_t)(jf*16 + (lane & 15))*128 + kb0;
    #pragma unroll
    for (int q = 0; q < 4; q++)
      acc2[jf] = __builtin_amdgcn_mfma_f32_16x16x32_f16(bf[q], *(const half8v*)(wp + q*32), acc2[jf], 0, 0, 0);
  }
  int r0 = n0 + ((lane >> 4) << 2);
  #pragma unroll
  for (int jf = 0; jf < 8; jf++) {
    int col = jf*16 + (lane & 15);
    float bv = b2v[col];
    #pragma unroll
    for (int r = 0; r < 4; r++)
      outB[(size_t)(r0 + r)*128 + col] = rrelu(acc2[jf][r] + bv);
  }
}

// ================= the cooperative mega-kernel =================
__global__ __launch_bounds__(512, 2) void coop_k(P p) {
  cg::grid_group grid = cg::this_grid();
  int blk = blockIdx.x, t = threadIdx.x;
  int lane = t & 63, wv = t >> 6;

  // ---- P0a: x-stats (block 0) + weight pack + zero sA1/cnt/bns (blocks 1..255)
  if (blk == 0) {
    if (wv < 8) {
      float s = 0.f, q = 0.f;
      for (int n = lane; n < N_NODES; n += 64) {
        float v = p.x[n*8 + wv];
        s += v; q += v*v;
      }
      #pragma unroll
      for (int o = 32; o > 0; o >>= 1) { s += __shfl_xor(s, o); q += __shfl_xor(q, o); }
      if (lane == 0) {
        float m = s / (float)N_NODES;
        p.mean[wv] = m;
        p.var[wv]  = q / (float)N_NODES - m*m;
      }
    }
  } else {
    for (int idx = (blk-1)*512 + t; idx < 131072; idx += 255*512) {
      if (idx < 49152) {
        int jj = idx >> 6, i = idx & 63;
        int k = jj >> 6, o = jj & 63;
        p.Wz1h[idx] = (f16)p.Wnn1[k*4096 + i*64 + o];
        p.Wih1h[idx < 12288 ? idx : 0] = (f16)p.Wih1[idx < 12288 ? idx : 0];
      }
      if (idx < 12288) p.Whh1h[idx] = (f16)p.Whh1[idx];
      if (idx < 8192) {
        int o = idx >> 6, i = idx & 63;
        p.Wc1Th[idx] = (f16)p.Wc1[i*128 + o];
      }
      if (idx < 16384) {
        int o = idx >> 7, i = idx & 127;
        p.Wc2Th[idx] = (f16)p.Wc2[i*128 + o];
      }
      if (idx < 131072) {
        int r = idx >> 7, i = idx & 127;
        int k = r >> 7, o = r & 127;
        p.W2fh[idx] = (f16)p.Wnn2[k*16384 + i*128 + o];
      }
      if (idx < 49152) { p.Wih2h[idx] = (f16)p.Wih2[idx]; p.Whh2h[idx] = (f16)p.Whh2[idx]; }
      if (idx < 131072) {
        int i = idx >> 9, j = idx & 511;
        float v = p.Ws_ih[(size_t)j*256 + i];
        if (i < 128) v += p.Ws_hh[(size_t)j*128 + i];
        p.Wfold[idx] = v;
      }
      if (idx < N_NODES) { p.cnt1[idx] = 0.f; p.cnt2[idx] = 0.f; }
      if (idx < 128) { p.bns1[idx] = 0.f; p.bns2[idx] = 0.f; }
      if (idx < 131072) ((float4*)p.sA1)[idx] = make_float4(0.f,0.f,0.f,0.f);
    }
  }
  grid.sync();

  // ---- P0b: node embed + edge embed + cnt atomics
  {
    int gtid = blk*512 + t;
    for (int idx = gtid; idx < N_NODES*64; idx += 131072) {
      int n = idx >> 6, o = idx & 63;
      float acc = p.bnode[o];
      #pragma unroll
      for (int i = 0; i < 8; i++) {
        float xn = (p.x[n*8+i] - p.mean[i]) * rsqrtf(p.var[i] + BN_EPS) * p.bnx_g[i] + p.bnx_b[i];
        acc += xn * p.Wn[i*64 + o];
      }
      p.nodeA[idx] = rrelu(acc);
    }
    for (int idx = gtid; idx < N_EDGES*12; idx += 131072) {
      int e = idx / 12, j = idx - e * 12;
      float acc = p.be[j];
      #pragma unroll
      for (int k = 0; k < 19; k++) acc += p.eattr[e*19+k] * p.We[k*12 + j];
      p.ea12[idx] = rrelu(acc);
    }
    if (gtid < N_EDGES) atomicAdd(&p.cnt1[p.ei[N_EDGES + gtid]], 1.0f);
    if (gtid < N_E3) {
      atomicAdd(&p.cnt2[p.ei3[N_E3 + gtid]], 1.0f);
      atomicAdd(&p.cnt2[p.ei3[gtid]], 1.0f);
    }
  }
  grid.sync();

  // ---- P1: conv1 (nodeA -> sA1); idle blocks zero sA2
  if (blk < 128) conv1f_body(p.nodeA, p.ei, p.ea12, p.Wz1h, p.sA1, blk, lane, wv);
  else if (blk < 144) zero_block(blk - 128, p.sA2, N_NODES*64);
  grid.sync();

  // ---- P2: GRU-1 iter 1 (sA1, nodeA -> nodeA2); idle blocks zero sB1
  if (blk < 64) gruf_body<6,0>(p.sA1, p.cnt1, p.bias1, p.Wih1h, p.Whh1h, p.bih1, p.bhh1,
                               p.nodeA, p.nodeA2, nullptr, nullptr, blk, lane, wv);
  else if (blk < 80) zero_block(blk - 64, p.sB1, N_NODES*128);
  grid.sync();

  // ---- P3: conv1 (nodeA2 -> sA2); idle blocks zero sB2
  if (blk < 128) conv1f_body(p.nodeA2, p.ei, p.ea12, p.Wz1h, p.sA2, blk, lane, wv);
  else if (blk < 144) zero_block(blk - 128, p.sB2, N_NODES*128);
  grid.sync();

  // ---- P4: GRU-1 iter 2 (+BN stats) (sA2, nodeA2 -> nodeA)
  if (blk < 64) gruf_body<6,1>(p.sA2, p.cnt1, p.bias1, p.Wih1h, p.Whh1h, p.bih1, p.bhh1,
                               p.nodeA2, p.nodeA, p.bns1, p.bns2, blk, lane, wv);
  grid.sync();

  // ---- P5: BN + FC1 + FC2 (nodeA -> nodeB)
  if (blk < 64) fcf_body(p.nodeA, p.Wc1Th, p.bc1, p.Wc2Th, p.bc2,
                         p.bns1, p.bns2, p.bnc_g, p.bnc_b, p.nodeB, blk, lane, wv);
  grid.sync();

  // ---- P6: conv2 (nodeB -> sB1)
  conv2f_body(p.nodeB, p.ei3, p.ea3, p.W2fh, p.sB1, blk, lane, wv);
  grid.sync();

  // ---- P7: GRU-2 iter 1 (sB1, nodeB -> nodeB2)
  if (blk < 128) gruf_body<7,0>(p.sB1, p.cnt2, p.bias2, p.Wih2h, p.Whh2h, p.bih2, p.bhh2,
                                p.nodeB, p.nodeB2, nullptr, nullptr, blk, lane, wv);
  grid.sync();

  // ---- P8: conv2 (nodeB2 -> sB2)
  conv2f_body(p.nodeB2, p.ei3, p.ea3, p.W2fh, p.sB2, blk, lane, wv);
  grid.sync();

  // ---- P9: GRU-2 iter 2 (sB2, nodeB2 -> nodeB)
  if (blk < 128) gruf_body<7,0>(p.sB2, p.cnt2, p.bias2, p.Wih2h, p.Whh2h, p.bih2, p.bhh2,
                                p.nodeB2, p.nodeB, nullptr, nullptr, blk, lane, wv);
}

// ================= standalone tail kernels =================
__global__ void bn_stats_k(const float* __restrict__ X, int nrow, int F,
                           float* __restrict__ mean, float* __restrict__ var) {
  int f = blockIdx.x, t = threadIdx.x;
  __shared__ float s1[256], s2[256];
  float a = 0.f, b = 0.f;
  for (int n = t; n < nrow; n += 256) {
    float v = X[(size_t)n * F + f];
    a += v; b += v * v;
  }
  s1[t] = a; s2[t] = b; __syncthreads();
  for (int w = 128; w > 0; w >>= 1) {
    if (t < w) { s1[t] += s1[t+w]; s2[t] += s2[t+w]; }
    __syncthreads();
  }
  if (t == 0) {
    float m = s1[0] / (float)nrow;
    mean[f] = m;
    var[f]  = s2[0] / (float)nrow - m * m;
  }
}

__global__ __launch_bounds__(1024) void set2set_k(const float* __restrict__ x,
    const float* __restrict__ Wfold,
    const float* __restrict__ bs_ih, const float* __restrict__ bs_hh,
    float* __restrict__ qpool) {
  int g = blockIdx.x, t = threadIdx.x;
  __shared__ float xs[NPG*128];
  __shared__ float hr[256];
  __shared__ float cbuf[128];
  __shared__ float pbuf[1024];
  __shared__ float abuf[NPG];
  *(float4*)&xs[t*4] = *(const float4*)(x + (size_t)g*NPG*128 + t*4);
  if (t < 128) {
    float gi = bs_ih[t]     + bs_hh[t];
    float gg = bs_ih[256+t] + bs_hh[256+t];
    float go = bs_ih[384+t] + bs_hh[384+t];
    float c0 = sigm(gi) * tanhf(gg);
    cbuf[t] = c0;
    hr[t] = sigm(go) * tanhf(c0);
  }
  __syncthreads();
  #pragma unroll 1
  for (int step = 0; step < 3; step++) {
    {
      int node = t >> 5, s = t & 31;
      const float* xr = xs + node*128 + s*4;
      float pv = xr[0]*hr[s*4] + xr[1]*hr[s*4+1] + xr[2]*hr[s*4+2] + xr[3]*hr[s*4+3];
      pv += __shfl_down(pv, 16, 32); pv += __shfl_down(pv, 8, 32);
      pv += __shfl_down(pv, 4, 32);  pv += __shfl_down(pv, 2, 32);
      pv += __shfl_down(pv, 1, 32);
      if (s == 0) pbuf[node] = pv;
    }
    __syncthreads();
    if (t < NPG) {
      float e = pbuf[t];
      float mx = e;
      for (int o = 16; o > 0; o >>= 1) mx = fmaxf(mx, __shfl_xor(mx, o, 32));
      float ex = __expf(e - mx);
      float den = ex;
      for (int o = 16; o > 0; o >>= 1) den += __shfl_xor(den, o, 32);
      abuf[t] = ex / den;
    }
    __syncthreads();
    if (t < 128) {
      float r = 0.f;
      #pragma unroll 8
      for (int nn = 0; nn < NPG; nn++) r += abuf[nn] * xs[nn*128 + t];
      hr[128 + t] = r;
    }
    __syncthreads();
    if (step == 2) break;
    {
      int j = t & 511, half = t >> 9;
      const float* wp = Wfold + (size_t)(half*128)*512 + j;
      const float* iv = hr + half*128;
      float a0=0.f, a1=0.f, a2=0.f, a3=0.f;
      #pragma unroll 4
      for (int i = 0; i < 128; i += 4) {
        a0 += iv[i]   * wp[(i)  *512];
        a1 += iv[i+1] * wp[(i+1)*512];
        a2 += iv[i+2] * wp[(i+2)*512];
        a3 += iv[i+3] * wp[(i+3)*512];
      }
      pbuf[t] = a0 + a1 + a2 + a3;
    }
    __syncthreads();
    if (t < 128) {
      float gi = pbuf[t]     + pbuf[512+t] + bs_ih[t]     + bs_hh[t];
      float gf = pbuf[128+t] + pbuf[640+t] + bs_ih[128+t] + bs_hh[128+t];
      float gg = pbuf[256+t] + pbuf[768+t] + bs_ih[256+t] + bs_hh[256+t];
      float go = pbuf[384+t] + pbuf[896+t] + bs_ih[384+t] + bs_hh[384+t];
      float ci = sigm(gf) * cbuf[t] + sigm(gi) * tanhf(gg);
      cbuf[t] = ci;
      hr[t] = sigm(go) * tanhf(ci);
    }
    __syncthreads();
  }
  if (t < 256) qpool[g*256 + t] = hr[t];
}

__global__ void yhat_k(const float* __restrict__ feat, const int* __restrict__ ei3,
                       const int* __restrict__ batch, const float* __restrict__ qpool,
                       float* __restrict__ yhat) {
  int idx = blockIdx.x * blockDim.x + threadIdx.x;
  if (idx >= N_E3 * 640) return;
  int e = idx / 640, j = idx - e * 640;
  int s0 = ei3[e], s1 = ei3[N_E3 + e];
  float v;
  if (j < 128)      { v = 0.5f * (feat[s0*128+j] + feat[s1*128+j]); }
  else if (j < 256) { int jj = j-128; v = feat[s0*128+jj] * feat[s1*128+jj]; }
  else if (j < 384) { int jj = j-256; float d = feat[s0*128+jj] - feat[s1*128+jj]; v = d*d; }
  else              { int cbi = batch[s0]; v = qpool[cbi*256 + (j-384)]; }
  yhat[idx] = v;
}

__global__ void final_k(const float* __restrict__ yhat,
                        const float* __restrict__ mean, const float* __restrict__ var,
                        const float* __restrict__ g, const float* __restrict__ b,
                        const float* __restrict__ ea3,
                        const float* __restrict__ Ww, const float* __restrict__ Wb,
                        float* __restrict__ out) {
  int e = blockIdx.x, t = threadIdx.x;
  __shared__ float red[128];
  float av[8];
  #pragma unroll
  for (int k = 0; k < 8; k++) av[k] = ea3[e*8 + k];
  float acc = 0.f;
  for (int j = t; j < 640; j += 128) {
    float yn = (yhat[(size_t)e*640 + j] - mean[j]) * rsqrtf(var[j] + BN_EPS) * g[j] + b[j];
    float wj = 0.f;
    #pragma unroll
    for (int k = 0; k < 8; k++) wj += av[k] * Ww[k*640 + j];
    acc += yn * wj;
  }
  red[t] = acc; __syncthreads();
  for (int w = 64; w > 0; w >>= 1) {
    if (t < w) red[t] += red[t+w];
    __syncthreads();
  }
  if (t == 0) {
    float bb = 0.f;
    #pragma unroll
    for (int k = 0; k < 8; k++) bb += av[k] * Wb[k];
    out[e] = red[0] + bb;
  }
}

extern "C" void kernel_launch(void* const* d_in, const int* in_sizes, int n_in,
                              void* d_out, int out_size, void* d_ws, size_t ws_size,
                              hipStream_t stream) {
  const float* x      = (const float*)d_in[0];
  const int*   ei     = (const int*)  d_in[1];
  const float* eattr  = (const float*)d_in[2];
  const int*   ei3    = (const int*)  d_in[3];
  const float* ea3    = (const float*)d_in[4];
  const int*   batch  = (const int*)  d_in[5];
  const float* bnx_g  = (const float*)d_in[6];
  const float* bnx_b  = (const float*)d_in[7];
  const float* Wn     = (const float*)d_in[8];
  const float* bnode  = (const float*)d_in[9];
  const float* We     = (const float*)d_in[10];
  const float* be     = (const float*)d_in[11];
  const float* Wnn1   = (const float*)d_in[12];
  const float* bias1  = (const float*)d_in[13];
  const float* Wih1   = (const float*)d_in[14];
  const float* Whh1   = (const float*)d_in[15];
  const float* bih1   = (const float*)d_in[16];
  const float* bhh1   = (const float*)d_in[17];
  const float* bnc_g  = (const float*)d_in[18];
  const float* bnc_b  = (const float*)d_in[19];
  const float* Wc1    = (const float*)d_in[20];
  const float* bc1    = (const float*)d_in[21];
  const float* Wc2    = (const float*)d_in[22];
  const float* bc2    = (const float*)d_in[23];
  const float* Wnn2   = (const float*)d_in[24];
  const float* bias2  = (const float*)d_in[25];
  const float* Wih2   = (const float*)d_in[26];
  const float* Whh2   = (const float*)d_in[27];
  const float* bih2   = (const float*)d_in[28];
  const float* bhh2   = (const float*)d_in[29];
  const float* Ws_ih  = (const float*)d_in[30];
  const float* Ws_hh  = (const float*)d_in[31];
  const float* bs_ih  = (const float*)d_in[32];
  const float* bs_hh  = (const float*)d_in[33];
  const float* bno_g  = (const float*)d_in[34];
  const float* bno_b  = (const float*)d_in[35];
  const float* Ww     = (const float*)d_in[36];
  const float* Wb     = (const float*)d_in[37];
  float* out = (float*)d_out;

  // workspace carve-up
  float* W = (float*)d_ws;
  size_t off = 0;
  float* Wfold  = W + off; off += 131072;
  float* ea12   = W + off; off += (size_t)N_EDGES * 12;
  float* nodeA  = W + off; off += (size_t)N_NODES * 64;
  float* nodeA2 = W + off; off += (size_t)N_NODES * 64;
  float* sA1    = W + off; off += (size_t)N_NODES * 64;
  float* sA2    = W + off; off += (size_t)N_NODES * 64;
  float* sB1    = W + off; off += (size_t)N_NODES * 128;
  float* sB2    = W + off; off += (size_t)N_NODES * 128;
  float* cnt1   = W + off; off += (size_t)N_NODES;
  float* cnt2   = W + off; off += (size_t)N_NODES;
  float* nodeB  = W + off; off += (size_t)N_NODES * 128;
  float* nodeB2 = W + off; off += (size_t)N_NODES * 128;
  float* qpool  = W + off; off += (size_t)NGRAPH * 256;
  float* yhat   = W + off; off += (size_t)N_E3 * 640;
  float* mean   = W + off; off += 640;
  float* var    = W + off; off += 640;
  float* bns1   = W + off; off += 128;
  float* bns2   = W + off; off += 128;
  f16* F = (f16*)(W + off);
  size_t foff = 0;
  f16* Wz1h  = F + foff; foff += 49152;
  f16* Wih1h = F + foff; foff += 12288;
  f16* Whh1h = F + foff; foff += 12288;
  f16* Wc1Th = F + foff; foff += 8192;
  f16* Wc2Th = F + foff; foff += 16384;
  f16* W2fh  = F + foff; foff += 131072;
  f16* Wih2h = F + foff; foff += 49152;
  f16* Whh2h = F + foff; foff += 49152;
  (void)foff; (void)ws_size; (void)in_sizes; (void)n_in; (void)out_size;

  P prm;
  prm.x = x; prm.eattr = eattr; prm.ea3 = ea3; prm.ei = ei; prm.ei3 = ei3;
  prm.bnx_g = bnx_g; prm.bnx_b = bnx_b; prm.Wn = Wn; prm.bnode = bnode;
  prm.We = We; prm.be = be;
  prm.Wnn1 = Wnn1; prm.bias1 = bias1; prm.Wih1 = Wih1; prm.Whh1 = Whh1;
  prm.bih1 = bih1; prm.bhh1 = bhh1;
  prm.bnc_g = bnc_g; prm.bnc_b = bnc_b; prm.Wc1 = Wc1; prm.bc1 = bc1;
  prm.Wc2 = Wc2; prm.bc2 = bc2;
  prm.Wnn2 = Wnn2; prm.bias2 = bias2; prm.Wih2 = Wih2; prm.Whh2 = Whh2;
  prm.bih2 = bih2; prm.bhh2 = bhh2;
  prm.Ws_ih = Ws_ih; prm.Ws_hh = Ws_hh;
  prm.mean = mean; prm.var = var; prm.ea12 = ea12;
  prm.nodeA = nodeA; prm.nodeA2 = nodeA2;
  prm.sA1 = sA1; prm.sA2 = sA2; prm.sB1 = sB1; prm.sB2 = sB2;
  prm.cnt1 = cnt1; prm.cnt2 = cnt2;
  prm.nodeB = nodeB; prm.nodeB2 = nodeB2;
  prm.bns1 = bns1; prm.bns2 = bns2; prm.Wfold = Wfold;
  prm.Wz1h = Wz1h; prm.Wih1h = Wih1h; prm.Whh1h = Whh1h;
  prm.Wc1Th = Wc1Th; prm.Wc2Th = Wc2Th; prm.W2fh = W2fh;
  prm.Wih2h = Wih2h; prm.Whh2h = Whh2h;

  void* kargs[] = { (void*)&prm };
  hipLaunchCooperativeKernel((const void*)coop_k, dim3(256), dim3(512), kargs, 0, stream);

  set2set_k<<<NGRAPH, 1024, 0, stream>>>(nodeB, Wfold, bs_ih, bs_hh, qpool);
  yhat_k<<<(N_E3*640 + 255)/256, 256, 0, stream>>>(nodeB, ei3, batch, qpool, yhat);
  bn_stats_k<<<640, 256, 0, stream>>>(yhat, N_E3, 640, mean, var);
  final_k<<<N_E3, 128, 0, stream>>>(yhat, mean, var, bno_g, bno_b, ea3, Ww, Wb, out);
}

// Round 11
// 241.202 us; speedup vs baseline: 2.2338x; 2.2338x over previous
//
#include <hip/hip_runtime.h>
#include <hip/hip_bf16.h>
#include <math.h>

#define N_NODES 8192
#define N_EDGES 16384
#define N_E3    1024
#define NGRAPH  256
#define NPG     32
#define SLOPE   (11.0f/48.0f)
#define BN_EPS  1e-5f

__device__ __forceinline__ float rrelu(float v){ return v >= 0.f ? v : SLOPE*v; }
__device__ __forceinline__ float sigm(float v){ return 1.f/(1.f+__expf(-v)); }

typedef _Float16 f16;
typedef __attribute__((ext_vector_type(8))) _Float16 half8v;
typedef __attribute__((ext_vector_type(4))) float f32x4;

__device__ __forceinline__ void zero_tail(int zb, float* zptr, int zcount) {
  float4 z4 = make_float4(0.f,0.f,0.f,0.f);
  int bd = blockDim.x;
  for (int i = zb*bd + (int)threadIdx.x; i*4 < zcount; i += 16*bd)
    ((float4*)zptr)[i] = z4;
}

// ======== conv1 fused: msg[e,o] = sum_kg ea[e,kg]*(nodeA[src[e]] @ W_kg)[o], atomic scatter
__global__ __launch_bounds__(256) void conv1f_k(const float* __restrict__ nodeA,
    const int* __restrict__ ei, const float* __restrict__ ea,
    const f16* __restrict__ Wz1h, float* __restrict__ sbuf) {
  int t = threadIdx.x, lane = t & 63, wv = t >> 6;
  int e0 = blockIdx.x*64 + wv*16;
  int eA = e0 + (lane & 15);
  int src = ei[eA];
  int kb0 = (lane >> 4) * 8;
  const float* ap = nodeA + (size_t)src*64 + kb0;
  float4 v0 = *(const float4*)ap,      v1 = *(const float4*)(ap+4);
  float4 v2 = *(const float4*)(ap+32), v3 = *(const float4*)(ap+36);
  half8v a0, a1;
  a0[0]=(f16)v0.x; a0[1]=(f16)v0.y; a0[2]=(f16)v0.z; a0[3]=(f16)v0.w;
  a0[4]=(f16)v1.x; a0[5]=(f16)v1.y; a0[6]=(f16)v1.z; a0[7]=(f16)v1.w;
  a1[0]=(f16)v2.x; a1[1]=(f16)v2.y; a1[2]=(f16)v2.z; a1[3]=(f16)v2.w;
  a1[4]=(f16)v3.x; a1[5]=(f16)v3.y; a1[6]=(f16)v3.z; a1[7]=(f16)v3.w;
  float eav[12];
  #pragma unroll
  for (int kg = 0; kg < 12; kg++) eav[kg] = ea[eA*12 + kg];

  f32x4 acc[4] = {{0,0,0,0},{0,0,0,0},{0,0,0,0},{0,0,0,0}};
  #pragma unroll
  for (int kg = 0; kg < 12; kg++) {
    f16 s = (f16)eav[kg];
    half8v s0, s1;
    #pragma unroll
    for (int u = 0; u < 8; u++) { s0[u] = a0[u]*s; s1[u] = a1[u]*s; }
    #pragma unroll
    for (int jf = 0; jf < 4; jf++) {
      const f16* wp = Wz1h + (size_t)(kg*64 + jf*16 + (lane & 15))*64 + kb0;
      acc[jf] = __builtin_amdgcn_mfma_f32_16x16x32_f16(s0, *(const half8v*)wp, acc[jf], 0, 0, 0);
      acc[jf] = __builtin_amdgcn_mfma_f32_16x16x32_f16(s1, *(const half8v*)(wp+32), acc[jf], 0, 0, 0);
    }
  }
  int dstv[4];
  #pragma unroll
  for (int r = 0; r < 4; r++) dstv[r] = ei[N_EDGES + e0 + ((lane>>4)<<2) + r];
  #pragma unroll
  for (int jf = 0; jf < 4; jf++) {
    int col = jf*16 + (lane & 15);
    #pragma unroll
    for (int r = 0; r < 4; r++)
      atomicAdd(&sbuf[dstv[r]*64 + col], acc[jf][r]);
  }
}

// ======== conv2 fused, parallelized: 256 blocks x 512 thr ========
__global__ __launch_bounds__(512) void conv2f_k(const float* __restrict__ nodeB,
    const int* __restrict__ ei3, const float* __restrict__ ea3,
    const f16* __restrict__ W2fh, float* __restrict__ sbuf) {
  int t = threadIdx.x, lane = t & 63, wv = t >> 6;
  int eg = blockIdx.x >> 1, qh = blockIdx.x & 1;
  int kgh = wv >> 2, jp = wv & 3;
  int e0 = eg * 16;
  int eA = e0 + (lane & 15);
  int src = ei3[eA];
  int kb0 = qh*64 + (lane >> 4) * 8;
  const float* ap = nodeB + (size_t)src*128 + kb0;
  half8v a0, a1;
  {
    float4 w0 = *(const float4*)ap,        w1 = *(const float4*)(ap+4);
    float4 w2 = *(const float4*)(ap + 32), w3 = *(const float4*)(ap+36);
    a0[0]=(f16)w0.x; a0[1]=(f16)w0.y; a0[2]=(f16)w0.z; a0[3]=(f16)w0.w;
    a0[4]=(f16)w1.x; a0[5]=(f16)w1.y; a0[6]=(f16)w1.z; a0[7]=(f16)w1.w;
    a1[0]=(f16)w2.x; a1[1]=(f16)w2.y; a1[2]=(f16)w2.z; a1[3]=(f16)w2.w;
    a1[4]=(f16)w3.x; a1[5]=(f16)w3.y; a1[6]=(f16)w3.z; a1[7]=(f16)w3.w;
  }
  int eb = eA & (N_E3 - 1);
  float eav[4];
  #pragma unroll
  for (int kk = 0; kk < 4; kk++) eav[kk] = ea3[eb*8 + kgh*4 + kk];

  f32x4 acc[2] = {{0,0,0,0},{0,0,0,0}};
  #pragma unroll
  for (int kk = 0; kk < 4; kk++) {
    f16 s = (f16)eav[kk];
    half8v s0, s1;
    #pragma unroll
    for (int u = 0; u < 8; u++) { s0[u] = a0[u]*s; s1[u] = a1[u]*s; }
    int kg = kgh*4 + kk;
    #pragma unroll
    for (int jj = 0; jj < 2; jj++) {
      int jf = jp*2 + jj;
      const f16* wp = W2fh + (size_t)(kg*128 + jf*16 + (lane & 15))*128 + kb0;
      acc[jj] = __builtin_amdgcn_mfma_f32_16x16x32_f16(s0, *(const half8v*)wp, acc[jj], 0, 0, 0);
      acc[jj] = __builtin_amdgcn_mfma_f32_16x16x32_f16(s1, *(const half8v*)(wp+32), acc[jj], 0, 0, 0);
    }
  }
  int dstv[4];
  #pragma unroll
  for (int r = 0; r < 4; r++) dstv[r] = ei3[(e0 + ((lane>>4)<<2) + r + N_E3) & (2*N_E3 - 1)];
  #pragma unroll
  for (int jj = 0; jj < 2; jj++) {
    int col = (jp*2+jj)*16 + (lane & 15);
    #pragma unroll
    for (int r = 0; r < 4; r++)
      atomicAdd(&sbuf[dstv[r]*128 + col], acc[jj][r]);
  }
}

// ======== fused GRU: both gate matmuls + combine; optional BN-stats; optional zero-tail
template<int LOGH, int STATS>
__global__ void gruf_k(const float* __restrict__ sbuf, const float* __restrict__ cnt,
                       const float* __restrict__ mbias,
                       const f16* __restrict__ Wih, const f16* __restrict__ Whh,
                       const float* __restrict__ bih, const float* __restrict__ bhh,
                       const float* __restrict__ hold, float* __restrict__ hnew,
                       float* __restrict__ bns1, float* __restrict__ bns2,
                       int nblk, float* __restrict__ zptr, int zcount) {
  if ((int)blockIdx.x >= nblk) { zero_tail(blockIdx.x - nblk, zptr, zcount); return; }
  const int H = 1 << LOGH;
  const int K = H;
  const int jt = H >> 6;
  int t = threadIdx.x;
  int lane = t & 63, wv = t >> 6;
  int wpb = blockDim.x >> 6;
  int bm = blockIdx.x / jt, bj = blockIdx.x % jt;
  int n0 = bm * (wpb << 4) + (wv << 4);
  int j0 = bj << 6;
  int row = n0 + (lane & 15);
  int kb0 = (lane >> 4) * 8;

  f32x4 aR[4]  = {{0,0,0,0},{0,0,0,0},{0,0,0,0},{0,0,0,0}};
  f32x4 aZ[4]  = {{0,0,0,0},{0,0,0,0},{0,0,0,0},{0,0,0,0}};
  f32x4 aIN[4] = {{0,0,0,0},{0,0,0,0},{0,0,0,0},{0,0,0,0}};
  f32x4 aHN[4] = {{0,0,0,0},{0,0,0,0},{0,0,0,0},{0,0,0,0}};

  float dn = 1.f / fmaxf(cnt[row], 1.0f);
  for (int k0 = 0; k0 < K; k0 += 32) {
    int kb = k0 + kb0;
    const float* ap = sbuf + (size_t)row * K + kb;
    float4 v0 = *(const float4*)ap, v1 = *(const float4*)(ap + 4);
    float4 b0 = *(const float4*)(mbias + kb), b1 = *(const float4*)(mbias + kb + 4);
    half8v af;
    af[0]=(f16)rrelu(v0.x*dn+b0.x); af[1]=(f16)rrelu(v0.y*dn+b0.y);
    af[2]=(f16)rrelu(v0.z*dn+b0.z); af[3]=(f16)rrelu(v0.w*dn+b0.w);
    af[4]=(f16)rrelu(v1.x*dn+b1.x); af[5]=(f16)rrelu(v1.y*dn+b1.y);
    af[6]=(f16)rrelu(v1.z*dn+b1.z); af[7]=(f16)rrelu(v1.w*dn+b1.w);
    #pragma unroll
    for (int jf = 0; jf < 4; jf++) {
      int wr = j0 + jf*16 + (lane & 15);
      half8v wR = *(const half8v*)(Wih + (size_t)wr*K + kb);
      half8v wZ = *(const half8v*)(Wih + (size_t)(H + wr)*K + kb);
      half8v wN = *(const half8v*)(Wih + (size_t)(2*H + wr)*K + kb);
      aR[jf]  = __builtin_amdgcn_mfma_f32_16x16x32_f16(af, wR, aR[jf], 0, 0, 0);
      aZ[jf]  = __builtin_amdgcn_mfma_f32_16x16x32_f16(af, wZ, aZ[jf], 0, 0, 0);
      aIN[jf] = __builtin_amdgcn_mfma_f32_16x16x32_f16(af, wN, aIN[jf], 0, 0, 0);
    }
  }
  for (int k0 = 0; k0 < K; k0 += 32) {
    int kb = k0 + kb0;
    const float* ap = hold + (size_t)row * K + kb;
    float4 v0 = *(const float4*)ap, v1 = *(const float4*)(ap + 4);
    half8v af;
    af[0]=(f16)v0.x; af[1]=(f16)v0.y; af[2]=(f16)v0.z; af[3]=(f16)v0.w;
    af[4]=(f16)v1.x; af[5]=(f16)v1.y; af[6]=(f16)v1.z; af[7]=(f16)v1.w;
    #pragma unroll
    for (int jf = 0; jf < 4; jf++) {
      int wr = j0 + jf*16 + (lane & 15);
      half8v wR = *(const half8v*)(Whh + (size_t)wr*K + kb);
      half8v wZ = *(const half8v*)(Whh + (size_t)(H + wr)*K + kb);
      half8v wN = *(const half8v*)(Whh + (size_t)(2*H + wr)*K + kb);
      aR[jf]  = __builtin_amdgcn_mfma_f32_16x16x32_f16(af, wR, aR[jf], 0, 0, 0);
      aZ[jf]  = __builtin_amdgcn_mfma_f32_16x16x32_f16(af, wZ, aZ[jf], 0, 0, 0);
      aHN[jf] = __builtin_amdgcn_mfma_f32_16x16x32_f16(af, wN, aHN[jf], 0, 0, 0);
    }
  }
  int r0 = n0 + ((lane >> 4) << 2);
  #pragma unroll
  for (int jf = 0; jf < 4; jf++) {
    int col = j0 + jf*16 + (lane & 15);
    float bR = bih[col] + bhh[col];
    float bZ = bih[H + col] + bhh[H + col];
    float bI = bih[2*H + col], bH = bhh[2*H + col];
    float ssum = 0.f, sq = 0.f;
    #pragma unroll
    for (int r = 0; r < 4; r++) {
      float rr = sigm(aR[jf][r] + bR);
      float zz = sigm(aZ[jf][r] + bZ);
      float nn = tanhf(aIN[jf][r] + bI + rr*(aHN[jf][r] + bH));
      float ho = hold[(size_t)(r0 + r)*H + col];
      float hv = (1.f - zz)*nn + zz*ho;
      hnew[(size_t)(r0 + r)*H + col] = hv;
      if (STATS) { ssum += hv; sq += hv*hv; }
    }
    if (STATS) {
      ssum += __shfl_xor(ssum, 16); ssum += __shfl_xor(ssum, 32);
      sq   += __shfl_xor(sq, 16);   sq   += __shfl_xor(sq, 32);
      if (lane < 16) { atomicAdd(&bns1[col], ssum); atomicAdd(&bns2[col], sq); }
    }
  }
}

// ======== fused FC1+FC2 ========
__global__ __launch_bounds__(256) void fcf_k(const float* __restrict__ A,
    const f16* __restrict__ W1, const float* __restrict__ b1v,
    const f16* __restrict__ W2, const float* __restrict__ b2v,
    const float* __restrict__ bns1, const float* __restrict__ bns2,
    const float* __restrict__ g, const float* __restrict__ b,
    float* __restrict__ outB,
    int nblk, float* __restrict__ zptr, int zcount) {
  if ((int)blockIdx.x >= nblk) { zero_tail(blockIdx.x - nblk, zptr, zcount); return; }
  __shared__ f16 y1s[4][16][128];
  int t = threadIdx.x, lane = t & 63, wv = t >> 6;
  int n0 = blockIdx.x*64 + wv*16;
  int row = n0 + (lane & 15);
  int kb0 = (lane >> 4) * 8;
  const float invN = 1.f / (float)N_NODES;

  const float* ap = A + (size_t)row*64 + kb0;
  half8v af0, af1;
  #pragma unroll
  for (int u = 0; u < 8; u++) {
    int k0i = kb0 + u, k1i = 32 + kb0 + u;
    float m0 = bns1[k0i]*invN, m1 = bns1[k1i]*invN;
    float va0 = bns2[k0i]*invN - m0*m0, va1 = bns2[k1i]*invN - m1*m1;
    af0[u] = (f16)((ap[u]    - m0)*rsqrtf(va0+BN_EPS)*g[k0i] + b[k0i]);
    af1[u] = (f16)((ap[32+u] - m1)*rsqrtf(va1+BN_EPS)*g[k1i] + b[k1i]);
  }
  f32x4 acc1[8] = {{0,0,0,0},{0,0,0,0},{0,0,0,0},{0,0,0,0},
                   {0,0,0,0},{0,0,0,0},{0,0,0,0},{0,0,0,0}};
  #pragma unroll
  for (int jf = 0; jf < 8; jf++) {
    const f16* wp = W1 + (size_t)(jf*16 + (lane & 15))*64 + kb0;
    acc1[jf] = __builtin_amdgcn_mfma_f32_16x16x32_f16(af0, *(const half8v*)wp, acc1[jf], 0, 0, 0);
    acc1[jf] = __builtin_amdgcn_mfma_f32_16x16x32_f16(af1, *(const half8v*)(wp+32), acc1[jf], 0, 0, 0);
  }
  #pragma unroll
  for (int jf = 0; jf < 8; jf++) {
    int col = jf*16 + (lane & 15);
    float bv = b1v[col];
    #pragma unroll
    for (int r = 0; r < 4; r++) {
      int rl = ((lane >> 4) << 2) + r;
      y1s[wv][rl][col] = (f16)rrelu(acc1[jf][r] + bv);
    }
  }
  __syncthreads();
  half8v bf[4];
  #pragma unroll
  for (int q = 0; q < 4; q++)
    bf[q] = *(const half8v*)&y1s[wv][lane & 15][q*32 + kb0];
  f32x4 acc2[8] = {{0,0,0,0},{0,0,0,0},{0,0,0,0},{0,0,0,0},
                   {0,0,0,0},{0,0,0,0},{0,0,0,0},{0,0,0,0}};
  #pragma unroll
  for (int jf = 0; jf < 8; jf++) {
    const f16* wp = W2 + (size_t)(jf*16 + (lane & 15))*128 + kb0;
    #pragma unroll
    for (int q = 0; q < 4; q++)
      acc2[jf] = __builtin_amdgcn_mfma_f32_16x16x32_f16(bf[q], *(const half8v*)(wp + q*32), acc2[jf], 0, 0, 0);
  }
  int r0 = n0 + ((lane >> 4) << 2);
  #pragma unroll
  for (int jf = 0; jf < 8; jf++) {
    int col = jf*16 + (lane & 15);
    float bv = b2v[col];
    #pragma unroll
    for (int r = 0; r < 4; r++)
      outB[(size_t)(r0 + r)*128 + col] = rrelu(acc2[jf][r] + bv);
  }
}

// ================= small kernels =================
// merged node-embed + edge-embed + cnt atomics + sA1 zero-tail
__global__ void embed_k(const float* __restrict__ x,
                        const float* __restrict__ mean, const float* __restrict__ var,
                        const float* __restrict__ g, const float* __restrict__ b,
                        const float* __restrict__ Wn, const float* __restrict__ bnode,
                        float* __restrict__ nodeA,
                        const float* __restrict__ eattr,
                        const float* __restrict__ We, const float* __restrict__ be,
                        float* __restrict__ ea12,
                        const int* __restrict__ ei, const int* __restrict__ ei3,
                        float* __restrict__ cnt1, float* __restrict__ cnt2,
                        float* __restrict__ zptr) {
  int bid = blockIdx.x, t = threadIdx.x;
  if (bid < 2048) {
    int idx = bid * 256 + t;
    int n = idx >> 6, o = idx & 63;
    float acc = bnode[o];
    #pragma unroll
    for (int i = 0; i < 8; i++) {
      float xn = (x[n*8+i] - mean[i]) * rsqrtf(var[i] + BN_EPS) * g[i] + b[i];
      acc += xn * Wn[i*64 + o];
    }
    nodeA[idx] = rrelu(acc);
  } else if (bid < 2816) {
    int idx = (bid - 2048) * 256 + t;
    if (idx >= N_EDGES * 12) return;
    int e = idx / 12, j = idx - e * 12;
    float acc = be[j];
    #pragma unroll
    for (int k = 0; k < 19; k++) acc += eattr[e*19+k] * We[k*12 + j];
    ea12[idx] = rrelu(acc);
  } else if (bid < 2880) {
    int idx = (bid - 2816) * 256 + t;
    if (idx < N_EDGES) atomicAdd(&cnt1[ei[N_EDGES + idx]], 1.0f);
    if (idx < N_E3) {
      atomicAdd(&cnt2[ei3[N_E3 + idx]], 1.0f);
      atomicAdd(&cnt2[ei3[idx]], 1.0f);
    }
  } else {
    zero_tail(bid - 2880, zptr, N_NODES*64);
  }
}

// packs: f16 weights [J,K] + fp32 Wfold + zero cnt/bns + x-BN-stats (block 512)
__global__ void pack_k(const float* __restrict__ Wnn1,
                       const float* __restrict__ Wih1, const float* __restrict__ Whh1,
                       const float* __restrict__ Wc1,  const float* __restrict__ Wc2,
                       const float* __restrict__ Wnn2,
                       const float* __restrict__ Wih2, const float* __restrict__ Whh2,
                       const float* __restrict__ Ws_ih, const float* __restrict__ Ws_hh,
                       const float* __restrict__ x,
                       f16* __restrict__ Wz1h,
                       f16* __restrict__ Wih1h, f16* __restrict__ Whh1h,
                       f16* __restrict__ Wc1Th, f16* __restrict__ Wc2Th,
                       f16* __restrict__ W2fh,
                       f16* __restrict__ Wih2h, f16* __restrict__ Whh2h,
                       float* __restrict__ Wfold,
                       float* __restrict__ cnt1, float* __restrict__ cnt2,
                       float* __restrict__ bns1, float* __restrict__ bns2,
                       float* __restrict__ mean, float* __restrict__ var) {
  if (blockIdx.x == 512) {
    // x-stats: wave wv handles features wv and wv+4
    int lane = threadIdx.x & 63, wv = threadIdx.x >> 6;
    #pragma unroll
    for (int h = 0; h < 2; h++) {
      int f = wv + h*4;
      float s = 0.f, q = 0.f;
      for (int n = lane; n < N_NODES; n += 64) {
        float v = x[n*8 + f];
        s += v; q += v*v;
      }
      #pragma unroll
      for (int o = 32; o > 0; o >>= 1) { s += __shfl_xor(s, o); q += __shfl_xor(q, o); }
      if (lane == 0) {
        float m = s / (float)N_NODES;
        mean[f] = m;
        var[f]  = q / (float)N_NODES - m*m;
      }
    }
    return;
  }
  int idx = blockIdx.x * 256 + threadIdx.x;
  if (idx < 49152) {
    int jj = idx >> 6, i = idx & 63;
    int k = jj >> 6, o = jj & 63;
    Wz1h[idx] = (f16)Wnn1[k*4096 + i*64 + o];
  }
  if (idx < 12288) { Wih1h[idx] = (f16)Wih1[idx]; Whh1h[idx] = (f16)Whh1[idx]; }
  if (idx < 8192) {
    int o = idx >> 6, i = idx & 63;
    Wc1Th[idx] = (f16)Wc1[i*128 + o];
  }
  if (idx < 16384) {
    int o = idx >> 7, i = idx & 127;
    Wc2Th[idx] = (f16)Wc2[i*128 + o];
  }
  if (idx < 131072) {
    int r = idx >> 7, i = idx & 127;
    int k = r >> 7, o = r & 127;
    W2fh[idx] = (f16)Wnn2[k*16384 + i*128 + o];
  }
  if (idx < 49152) { Wih2h[idx] = (f16)Wih2[idx]; Whh2h[idx] = (f16)Whh2[idx]; }
  if (idx < 131072) {
    int i = idx >> 9, j = idx & 511;
    float v = Ws_ih[(size_t)j*256 + i];
    if (i < 128) v += Ws_hh[(size_t)j*128 + i];
    Wfold[idx] = v;
  }
  if (idx < N_NODES) { cnt1[idx] = 0.f; cnt2[idx] = 0.f; }
  if (idx < 128) { bns1[idx] = 0.f; bns2[idx] = 0.f; }
}

// ---------- Set2Set ----------
__global__ __launch_bounds__(1024) void set2set_k(const float* __restrict__ x,
    const float* __restrict__ Wfold,
    const float* __restrict__ bs_ih, const float* __restrict__ bs_hh,
    float* __restrict__ qpool) {
  int g = blockIdx.x, t = threadIdx.x;
  __shared__ float xs[NPG*128];
  __shared__ float hr[256];
  __shared__ float cbuf[128];
  __shared__ float pbuf[1024];
  __shared__ float abuf[NPG];
  *(float4*)&xs[t*4] = *(const float4*)(x + (size_t)g*NPG*128 + t*4);
  if (t < 128) {
    float gi = bs_ih[t]     + bs_hh[t];
    float gg = bs_ih[256+t] + bs_hh[256+t];
    float go = bs_ih[384+t] + bs_hh[384+t];
    float c0 = sigm(gi) * tanhf(gg);
    cbuf[t] = c0;
    hr[t] = sigm(go) * tanhf(c0);
  }
  __syncthreads();
  #pragma unroll 1
  for (int step = 0; step < 3; step++) {
    {
      int node = t >> 5, s = t & 31;
      const float* xr = xs + node*128 + s*4;
      float pv = xr[0]*hr[s*4] + xr[1]*hr[s*4+1] + xr[2]*hr[s*4+2] + xr[3]*hr[s*4+3];
      pv += __shfl_down(pv, 16, 32); pv += __shfl_down(pv, 8, 32);
      pv += __shfl_down(pv, 4, 32);  pv += __shfl_down(pv, 2, 32);
      pv += __shfl_down(pv, 1, 32);
      if (s == 0) pbuf[node] = pv;
    }
    __syncthreads();
    if (t < NPG) {
      float e = pbuf[t];
      float mx = e;
      for (int o = 16; o > 0; o >>= 1) mx = fmaxf(mx, __shfl_xor(mx, o, 32));
      float ex = __expf(e - mx);
      float den = ex;
      for (int o = 16; o > 0; o >>= 1) den += __shfl_xor(den, o, 32);
      abuf[t] = ex / den;
    }
    __syncthreads();
    if (t < 128) {
      float r = 0.f;
      #pragma unroll 8
      for (int nn = 0; nn < NPG; nn++) r += abuf[nn] * xs[nn*128 + t];
      hr[128 + t] = r;
    }
    __syncthreads();
    if (step == 2) break;
    {
      int j = t & 511, half = t >> 9;
      const float* wp = Wfold + (size_t)(half*128)*512 + j;
      const float* iv = hr + half*128;
      float a0=0.f, a1=0.f, a2=0.f, a3=0.f;
      #pragma unroll 4
      for (int i = 0; i < 128; i += 4) {
        a0 += iv[i]   * wp[(i)  *512];
        a1 += iv[i+1] * wp[(i+1)*512];
        a2 += iv[i+2] * wp[(i+2)*512];
        a3 += iv[i+3] * wp[(i+3)*512];
      }
      pbuf[t] = a0 + a1 + a2 + a3;
    }
    __syncthreads();
    if (t < 128) {
      float gi = pbuf[t]     + pbuf[512+t] + bs_ih[t]     + bs_hh[t];
      float gf = pbuf[128+t] + pbuf[640+t] + bs_ih[128+t] + bs_hh[128+t];
      float gg = pbuf[256+t] + pbuf[768+t] + bs_ih[256+t] + bs_hh[256+t];
      float go = pbuf[384+t] + pbuf[896+t] + bs_ih[384+t] + bs_hh[384+t];
      float ci = sigm(gf) * cbuf[t] + sigm(gi) * tanhf(gg);
      cbuf[t] = ci;
      hr[t] = sigm(go) * tanhf(ci);
    }
    __syncthreads();
  }
  if (t < 256) qpool[g*256 + t] = hr[t];
}

// ======== yhat + per-column BN stats fused: one wave per column ========
__global__ __launch_bounds__(256) void ys_k(const float* __restrict__ feat,
    const int* __restrict__ ei3, const int* __restrict__ batch,
    const float* __restrict__ qpool,
    float* __restrict__ yhat, float* __restrict__ mean, float* __restrict__ var) {
  int t = threadIdx.x, lane = t & 63, wv = t >> 6;
  int j = blockIdx.x*4 + wv;          // 160 blocks * 4 waves = 640 columns
  float s = 0.f, q = 0.f;
  for (int e = lane; e < N_E3; e += 64) {
    int s0 = ei3[e], s1 = ei3[N_E3 + e];
    float v;
    if (j < 128)      { v = 0.5f * (feat[s0*128+j] + feat[s1*128+j]); }
    else if (j < 256) { int jj = j-128; v = feat[s0*128+jj] * feat[s1*128+jj]; }
    else if (j < 384) { int jj = j-256; float d = feat[s0*128+jj] - feat[s1*128+jj]; v = d*d; }
    else              { int cbi = batch[s0]; v = qpool[cbi*256 + (j-384)]; }
    yhat[(size_t)e*640 + j] = v;
    s += v; q += v*v;
  }
  #pragma unroll
  for (int o = 32; o > 0; o >>= 1) { s += __shfl_xor(s, o); q += __shfl_xor(q, o); }
  if (lane == 0) {
    float m = s / (float)N_E3;
    mean[j] = m;
    var[j]  = q / (float)N_E3 - m*m;
  }
}

__global__ void final_k(const float* __restrict__ yhat,
                        const float* __restrict__ mean, const float* __restrict__ var,
                        const float* __restrict__ g, const float* __restrict__ b,
                        const float* __restrict__ ea3,
                        const float* __restrict__ Ww, const float* __restrict__ Wb,
                        float* __restrict__ out) {
  int e = blockIdx.x, t = threadIdx.x;
  __shared__ float red[128];
  float av[8];
  #pragma unroll
  for (int k = 0; k < 8; k++) av[k] = ea3[e*8 + k];
  float acc = 0.f;
  for (int j = t; j < 640; j += 128) {
    float yn = (yhat[(size_t)e*640 + j] - mean[j]) * rsqrtf(var[j] + BN_EPS) * g[j] + b[j];
    float wj = 0.f;
    #pragma unroll
    for (int k = 0; k < 8; k++) wj += av[k] * Ww[k*640 + j];
    acc += yn * wj;
  }
  red[t] = acc; __syncthreads();
  for (int w = 64; w > 0; w >>= 1) {
    if (t < w) red[t] += red[t+w];
    __syncthreads();
  }
  if (t == 0) {
    float bb = 0.f;
    #pragma unroll
    for (int k = 0; k < 8; k++) bb += av[k] * Wb[k];
    out[e] = red[0] + bb;
  }
}

extern "C" void kernel_launch(void* const* d_in, const int* in_sizes, int n_in,
                              void* d_out, int out_size, void* d_ws, size_t ws_size,
                              hipStream_t stream) {
  const float* x      = (const float*)d_in[0];
  const int*   ei     = (const int*)  d_in[1];
  const float* eattr  = (const float*)d_in[2];
  const int*   ei3    = (const int*)  d_in[3];
  const float* ea3    = (const float*)d_in[4];
  const int*   batch  = (const int*)  d_in[5];
  const float* bnx_g  = (const float*)d_in[6];
  const float* bnx_b  = (const float*)d_in[7];
  const float* Wn     = (const float*)d_in[8];
  const float* bnode  = (const float*)d_in[9];
  const float* We     = (const float*)d_in[10];
  const float* be     = (const float*)d_in[11];
  const float* Wnn1   = (const float*)d_in[12];
  const float* bias1  = (const float*)d_in[13];
  const float* Wih1   = (const float*)d_in[14];
  const float* Whh1   = (const float*)d_in[15];
  const float* bih1   = (const float*)d_in[16];
  const float* bhh1   = (const float*)d_in[17];
  const float* bnc_g  = (const float*)d_in[18];
  const float* bnc_b  = (const float*)d_in[19];
  const float* Wc1    = (const float*)d_in[20];
  const float* bc1    = (const float*)d_in[21];
  const float* Wc2    = (const float*)d_in[22];
  const float* bc2    = (const float*)d_in[23];
  const float* Wnn2   = (const float*)d_in[24];
  const float* bias2  = (const float*)d_in[25];
  const float* Wih2   = (const float*)d_in[26];
  const float* Whh2   = (const float*)d_in[27];
  const float* bih2   = (const float*)d_in[28];
  const float* bhh2   = (const float*)d_in[29];
  const float* Ws_ih  = (const float*)d_in[30];
  const float* Ws_hh  = (const float*)d_in[31];
  const float* bs_ih  = (const float*)d_in[32];
  const float* bs_hh  = (const float*)d_in[33];
  const float* bno_g  = (const float*)d_in[34];
  const float* bno_b  = (const float*)d_in[35];
  const float* Ww     = (const float*)d_in[36];
  const float* Wb     = (const float*)d_in[37];
  float* out = (float*)d_out;

  // workspace carve-up
  float* W = (float*)d_ws;
  size_t off = 0;
  float* Wfold  = W + off; off += 131072;
  float* ea12   = W + off; off += (size_t)N_EDGES * 12;
  float* nodeA  = W + off; off += (size_t)N_NODES * 64;
  float* nodeA2 = W + off; off += (size_t)N_NODES * 64;
  float* sA1    = W + off; off += (size_t)N_NODES * 64;
  float* sA2    = W + off; off += (size_t)N_NODES * 64;
  float* sB1    = W + off; off += (size_t)N_NODES * 128;
  float* sB2    = W + off; off += (size_t)N_NODES * 128;
  float* cnt1   = W + off; off += (size_t)N_NODES;
  float* cnt2   = W + off; off += (size_t)N_NODES;
  float* nodeB  = W + off; off += (size_t)N_NODES * 128;
  float* nodeB2 = W + off; off += (size_t)N_NODES * 128;
  float* qpool  = W + off; off += (size_t)NGRAPH * 256;
  float* yhat   = W + off; off += (size_t)N_E3 * 640;
  float* mean   = W + off; off += 640;
  float* var    = W + off; off += 640;
  float* bns1   = W + off; off += 128;
  float* bns2   = W + off; off += 128;
  f16* F = (f16*)(W + off);
  size_t foff = 0;
  f16* Wz1h  = F + foff; foff += 49152;
  f16* Wih1h = F + foff; foff += 12288;
  f16* Whh1h = F + foff; foff += 12288;
  f16* Wc1Th = F + foff; foff += 8192;
  f16* Wc2Th = F + foff; foff += 16384;
  f16* W2fh  = F + foff; foff += 131072;
  f16* Wih2h = F + foff; foff += 49152;
  f16* Whh2h = F + foff; foff += 49152;
  (void)foff; (void)ws_size; (void)in_sizes; (void)n_in; (void)out_size;

  // 1. pack (+zero cnt/bns, +x-stats in block 512)
  pack_k<<<513, 256, 0, stream>>>(Wnn1, Wih1, Whh1, Wc1, Wc2, Wnn2, Wih2, Whh2, Ws_ih, Ws_hh, x,
                                  Wz1h, Wih1h, Whh1h, Wc1Th, Wc2Th, W2fh, Wih2h, Whh2h,
                                  Wfold, cnt1, cnt2, bns1, bns2, mean, var);
  // 2. embeds (+cnt atomics, +zero sA1)
  embed_k<<<2896, 256, 0, stream>>>(x, mean, var, bnx_g, bnx_b, Wn, bnode, nodeA,
                                    eattr, We, be, ea12, ei, ei3, cnt1, cnt2, sA1);

  // 3-6. layer-1 x2 (ping-pong h and sbuf)
  conv1f_k<<<256, 256, 0, stream>>>(nodeA, ei, ea12, Wz1h, sA1);
  gruf_k<6,0><<<272, 128, 0, stream>>>(sA1, cnt1, bias1, Wih1h, Whh1h, bih1, bhh1,
                                       nodeA, nodeA2, nullptr, nullptr,
                                       256, sA2, N_NODES*64);
  conv1f_k<<<256, 256, 0, stream>>>(nodeA2, ei, ea12, Wz1h, sA2);
  gruf_k<6,1><<<272, 128, 0, stream>>>(sA2, cnt1, bias1, Wih1h, Whh1h, bih1, bhh1,
                                       nodeA2, nodeA, bns1, bns2,
                                       256, sB1, N_NODES*128);

  // 7. fused BN + FC1 + FC2 (+zero sB2)
  fcf_k<<<144, 256, 0, stream>>>(nodeA, Wc1Th, bc1, Wc2Th, bc2,
                                 bns1, bns2, bnc_g, bnc_b, nodeB,
                                 128, sB2, N_NODES*128);

  // 8-11. layer-2 x2
  conv2f_k<<<256, 512, 0, stream>>>(nodeB, ei3, ea3, W2fh, sB1);
  gruf_k<7,0><<<256, 256, 0, stream>>>(sB1, cnt2, bias2, Wih2h, Whh2h, bih2, bhh2,
                                       nodeB, nodeB2, nullptr, nullptr,
                                       256, nullptr, 0);
  conv2f_k<<<256, 512, 0, stream>>>(nodeB2, ei3, ea3, W2fh, sB2);
  gruf_k<7,0><<<256, 256, 0, stream>>>(sB2, cnt2, bias2, Wih2h, Whh2h, bih2, bhh2,
                                       nodeB2, nodeB, nullptr, nullptr,
                                       256, nullptr, 0);

  // 12. set2set
  set2set_k<<<NGRAPH, 1024, 0, stream>>>(nodeB, Wfold, bs_ih, bs_hh, qpool);

  // 13. yhat + column stats (fused)
  ys_k<<<160, 256, 0, stream>>>(nodeB, ei3, batch, qpool, yhat, mean, var);

  // 14. weighted sum
  final_k<<<N_E3, 128, 0, stream>>>(yhat, mean, var, bno_g, bno_b, ea3, Ww, Wb, out);
}

// Round 12
// 201.116 us; speedup vs baseline: 2.6790x; 1.1993x over previous
//
#include <hip/hip_runtime.h>
#include <hip/hip_bf16.h>
#include <math.h>

#define N_NODES 8192
#define N_EDGES 16384
#define N_E3    1024
#define NGRAPH  256
#define NPG     32
#define SLOPE   (11.0f/48.0f)
#define BN_EPS  1e-5f

__device__ __forceinline__ float rrelu(float v){ return v >= 0.f ? v : SLOPE*v; }
__device__ __forceinline__ float sigm(float v){ return 1.f/(1.f+__expf(-v)); }

typedef _Float16 f16;
typedef __attribute__((ext_vector_type(8))) _Float16 half8v;
typedef __attribute__((ext_vector_type(4))) float f32x4;

__device__ __forceinline__ void zero_tail(int zb, float* zptr, int zcount) {
  float4 z4 = make_float4(0.f,0.f,0.f,0.f);
  int bd = blockDim.x;
  for (int i = zb*bd + (int)threadIdx.x; i*4 < zcount; i += 16*bd)
    ((float4*)zptr)[i] = z4;
}

// ======== conv1 fused: msg[e,o] = sum_kg ea[e,kg]*(nodeA[src[e]] @ W_kg)[o], atomic scatter
__global__ __launch_bounds__(256) void conv1f_k(const float* __restrict__ nodeA,
    const int* __restrict__ ei, const float* __restrict__ ea,
    const f16* __restrict__ Wz1h, float* __restrict__ sbuf) {
  int t = threadIdx.x, lane = t & 63, wv = t >> 6;
  int e0 = blockIdx.x*64 + wv*16;
  int eA = e0 + (lane & 15);
  int src = ei[eA];
  int kb0 = (lane >> 4) * 8;
  const float* ap = nodeA + (size_t)src*64 + kb0;
  float4 v0 = *(const float4*)ap,      v1 = *(const float4*)(ap+4);
  float4 v2 = *(const float4*)(ap+32), v3 = *(const float4*)(ap+36);
  half8v a0, a1;
  a0[0]=(f16)v0.x; a0[1]=(f16)v0.y; a0[2]=(f16)v0.z; a0[3]=(f16)v0.w;
  a0[4]=(f16)v1.x; a0[5]=(f16)v1.y; a0[6]=(f16)v1.z; a0[7]=(f16)v1.w;
  a1[0]=(f16)v2.x; a1[1]=(f16)v2.y; a1[2]=(f16)v2.z; a1[3]=(f16)v2.w;
  a1[4]=(f16)v3.x; a1[5]=(f16)v3.y; a1[6]=(f16)v3.z; a1[7]=(f16)v3.w;
  float eav[12];
  #pragma unroll
  for (int kg = 0; kg < 12; kg++) eav[kg] = ea[eA*12 + kg];

  f32x4 acc[4] = {{0,0,0,0},{0,0,0,0},{0,0,0,0},{0,0,0,0}};
  #pragma unroll
  for (int kg = 0; kg < 12; kg++) {
    f16 s = (f16)eav[kg];
    half8v s0, s1;
    #pragma unroll
    for (int u = 0; u < 8; u++) { s0[u] = a0[u]*s; s1[u] = a1[u]*s; }
    #pragma unroll
    for (int jf = 0; jf < 4; jf++) {
      const f16* wp = Wz1h + (size_t)(kg*64 + jf*16 + (lane & 15))*64 + kb0;
      acc[jf] = __builtin_amdgcn_mfma_f32_16x16x32_f16(s0, *(const half8v*)wp, acc[jf], 0, 0, 0);
      acc[jf] = __builtin_amdgcn_mfma_f32_16x16x32_f16(s1, *(const half8v*)(wp+32), acc[jf], 0, 0, 0);
    }
  }
  int dstv[4];
  #pragma unroll
  for (int r = 0; r < 4; r++) dstv[r] = ei[N_EDGES + e0 + ((lane>>4)<<2) + r];
  #pragma unroll
  for (int jf = 0; jf < 4; jf++) {
    int col = jf*16 + (lane & 15);
    #pragma unroll
    for (int r = 0; r < 4; r++)
      atomicAdd(&sbuf[dstv[r]*64 + col], acc[jf][r]);
  }
}

// ======== conv2 fused, parallelized: 256 blocks x 512 thr ========
__global__ __launch_bounds__(512) void conv2f_k(const float* __restrict__ nodeB,
    const int* __restrict__ ei3, const float* __restrict__ ea3,
    const f16* __restrict__ W2fh, float* __restrict__ sbuf) {
  int t = threadIdx.x, lane = t & 63, wv = t >> 6;
  int eg = blockIdx.x >> 1, qh = blockIdx.x & 1;
  int kgh = wv >> 2, jp = wv & 3;
  int e0 = eg * 16;
  int eA = e0 + (lane & 15);
  int src = ei3[eA];
  int kb0 = qh*64 + (lane >> 4) * 8;
  const float* ap = nodeB + (size_t)src*128 + kb0;
  half8v a0, a1;
  {
    float4 w0 = *(const float4*)ap,        w1 = *(const float4*)(ap+4);
    float4 w2 = *(const float4*)(ap + 32), w3 = *(const float4*)(ap+36);
    a0[0]=(f16)w0.x; a0[1]=(f16)w0.y; a0[2]=(f16)w0.z; a0[3]=(f16)w0.w;
    a0[4]=(f16)w1.x; a0[5]=(f16)w1.y; a0[6]=(f16)w1.z; a0[7]=(f16)w1.w;
    a1[0]=(f16)w2.x; a1[1]=(f16)w2.y; a1[2]=(f16)w2.z; a1[3]=(f16)w2.w;
    a1[4]=(f16)w3.x; a1[5]=(f16)w3.y; a1[6]=(f16)w3.z; a1[7]=(f16)w3.w;
  }
  int eb = eA & (N_E3 - 1);
  float eav[4];
  #pragma unroll
  for (int kk = 0; kk < 4; kk++) eav[kk] = ea3[eb*8 + kgh*4 + kk];

  f32x4 acc[2] = {{0,0,0,0},{0,0,0,0}};
  #pragma unroll
  for (int kk = 0; kk < 4; kk++) {
    f16 s = (f16)eav[kk];
    half8v s0, s1;
    #pragma unroll
    for (int u = 0; u < 8; u++) { s0[u] = a0[u]*s; s1[u] = a1[u]*s; }
    int kg = kgh*4 + kk;
    #pragma unroll
    for (int jj = 0; jj < 2; jj++) {
      int jf = jp*2 + jj;
      const f16* wp = W2fh + (size_t)(kg*128 + jf*16 + (lane & 15))*128 + kb0;
      acc[jj] = __builtin_amdgcn_mfma_f32_16x16x32_f16(s0, *(const half8v*)wp, acc[jj], 0, 0, 0);
      acc[jj] = __builtin_amdgcn_mfma_f32_16x16x32_f16(s1, *(const half8v*)(wp+32), acc[jj], 0, 0, 0);
    }
  }
  int dstv[4];
  #pragma unroll
  for (int r = 0; r < 4; r++) dstv[r] = ei3[(e0 + ((lane>>4)<<2) + r + N_E3) & (2*N_E3 - 1)];
  #pragma unroll
  for (int jj = 0; jj < 2; jj++) {
    int col = (jp*2+jj)*16 + (lane & 15);
    #pragma unroll
    for (int r = 0; r < 4; r++)
      atomicAdd(&sbuf[dstv[r]*128 + col], acc[jj][r]);
  }
}

// ======== fused GRU: both gate matmuls + combine; optional BN-stats; optional zero-tail
template<int LOGH, int STATS>
__global__ void gruf_k(const float* __restrict__ sbuf, const float* __restrict__ cnt,
                       const float* __restrict__ mbias,
                       const f16* __restrict__ Wih, const f16* __restrict__ Whh,
                       const float* __restrict__ bih, const float* __restrict__ bhh,
                       const float* __restrict__ hold, float* __restrict__ hnew,
                       float* __restrict__ bns1, float* __restrict__ bns2,
                       int nblk, float* __restrict__ zptr, int zcount) {
  if ((int)blockIdx.x >= nblk) { zero_tail(blockIdx.x - nblk, zptr, zcount); return; }
  const int H = 1 << LOGH;
  const int K = H;
  const int jt = H >> 6;
  int t = threadIdx.x;
  int lane = t & 63, wv = t >> 6;
  int wpb = blockDim.x >> 6;
  int bm = blockIdx.x / jt, bj = blockIdx.x % jt;
  int n0 = bm * (wpb << 4) + (wv << 4);
  int j0 = bj << 6;
  int row = n0 + (lane & 15);
  int kb0 = (lane >> 4) * 8;

  f32x4 aR[4]  = {{0,0,0,0},{0,0,0,0},{0,0,0,0},{0,0,0,0}};
  f32x4 aZ[4]  = {{0,0,0,0},{0,0,0,0},{0,0,0,0},{0,0,0,0}};
  f32x4 aIN[4] = {{0,0,0,0},{0,0,0,0},{0,0,0,0},{0,0,0,0}};
  f32x4 aHN[4] = {{0,0,0,0},{0,0,0,0},{0,0,0,0},{0,0,0,0}};

  float dn = 1.f / fmaxf(cnt[row], 1.0f);
  for (int k0 = 0; k0 < K; k0 += 32) {
    int kb = k0 + kb0;
    const float* ap = sbuf + (size_t)row * K + kb;
    float4 v0 = *(const float4*)ap, v1 = *(const float4*)(ap + 4);
    float4 b0 = *(const float4*)(mbias + kb), b1 = *(const float4*)(mbias + kb + 4);
    half8v af;
    af[0]=(f16)rrelu(v0.x*dn+b0.x); af[1]=(f16)rrelu(v0.y*dn+b0.y);
    af[2]=(f16)rrelu(v0.z*dn+b0.z); af[3]=(f16)rrelu(v0.w*dn+b0.w);
    af[4]=(f16)rrelu(v1.x*dn+b1.x); af[5]=(f16)rrelu(v1.y*dn+b1.y);
    af[6]=(f16)rrelu(v1.z*dn+b1.z); af[7]=(f16)rrelu(v1.w*dn+b1.w);
    #pragma unroll
    for (int jf = 0; jf < 4; jf++) {
      int wr = j0 + jf*16 + (lane & 15);
      half8v wR = *(const half8v*)(Wih + (size_t)wr*K + kb);
      half8v wZ = *(const half8v*)(Wih + (size_t)(H + wr)*K + kb);
      half8v wN = *(const half8v*)(Wih + (size_t)(2*H + wr)*K + kb);
      aR[jf]  = __builtin_amdgcn_mfma_f32_16x16x32_f16(af, wR, aR[jf], 0, 0, 0);
      aZ[jf]  = __builtin_amdgcn_mfma_f32_16x16x32_f16(af, wZ, aZ[jf], 0, 0, 0);
      aIN[jf] = __builtin_amdgcn_mfma_f32_16x16x32_f16(af, wN, aIN[jf], 0, 0, 0);
    }
  }
  for (int k0 = 0; k0 < K; k0 += 32) {
    int kb = k0 + kb0;
    const float* ap = hold + (size_t)row * K + kb;
    float4 v0 = *(const float4*)ap, v1 = *(const float4*)(ap + 4);
    half8v af;
    af[0]=(f16)v0.x; af[1]=(f16)v0.y; af[2]=(f16)v0.z; af[3]=(f16)v0.w;
    af[4]=(f16)v1.x; af[5]=(f16)v1.y; af[6]=(f16)v1.z; af[7]=(f16)v1.w;
    #pragma unroll
    for (int jf = 0; jf < 4; jf++) {
      int wr = j0 + jf*16 + (lane & 15);
      half8v wR = *(const half8v*)(Whh + (size_t)wr*K + kb);
      half8v wZ = *(const half8v*)(Whh + (size_t)(H + wr)*K + kb);
      half8v wN = *(const half8v*)(Whh + (size_t)(2*H + wr)*K + kb);
      aR[jf]  = __builtin_amdgcn_mfma_f32_16x16x32_f16(af, wR, aR[jf], 0, 0, 0);
      aZ[jf]  = __builtin_amdgcn_mfma_f32_16x16x32_f16(af, wZ, aZ[jf], 0, 0, 0);
      aHN[jf] = __builtin_amdgcn_mfma_f32_16x16x32_f16(af, wN, aHN[jf], 0, 0, 0);
    }
  }
  int r0 = n0 + ((lane >> 4) << 2);
  #pragma unroll
  for (int jf = 0; jf < 4; jf++) {
    int col = j0 + jf*16 + (lane & 15);
    float bR = bih[col] + bhh[col];
    float bZ = bih[H + col] + bhh[H + col];
    float bI = bih[2*H + col], bH = bhh[2*H + col];
    float ssum = 0.f, sq = 0.f;
    #pragma unroll
    for (int r = 0; r < 4; r++) {
      float rr = sigm(aR[jf][r] + bR);
      float zz = sigm(aZ[jf][r] + bZ);
      float nn = tanhf(aIN[jf][r] + bI + rr*(aHN[jf][r] + bH));
      float ho = hold[(size_t)(r0 + r)*H + col];
      float hv = (1.f - zz)*nn + zz*ho;
      hnew[(size_t)(r0 + r)*H + col] = hv;
      if (STATS) { ssum += hv; sq += hv*hv; }
    }
    if (STATS) {
      ssum += __shfl_xor(ssum, 16); ssum += __shfl_xor(ssum, 32);
      sq   += __shfl_xor(sq, 16);   sq   += __shfl_xor(sq, 32);
      if (lane < 16) { atomicAdd(&bns1[col], ssum); atomicAdd(&bns2[col], sq); }
    }
  }
}

// ======== fused FC1+FC2 ========
__global__ __launch_bounds__(256) void fcf_k(const float* __restrict__ A,
    const f16* __restrict__ W1, const float* __restrict__ b1v,
    const f16* __restrict__ W2, const float* __restrict__ b2v,
    const float* __restrict__ bns1, const float* __restrict__ bns2,
    const float* __restrict__ g, const float* __restrict__ b,
    float* __restrict__ outB,
    int nblk, float* __restrict__ zptr, int zcount) {
  if ((int)blockIdx.x >= nblk) { zero_tail(blockIdx.x - nblk, zptr, zcount); return; }
  __shared__ f16 y1s[4][16][128];
  int t = threadIdx.x, lane = t & 63, wv = t >> 6;
  int n0 = blockIdx.x*64 + wv*16;
  int row = n0 + (lane & 15);
  int kb0 = (lane >> 4) * 8;
  const float invN = 1.f / (float)N_NODES;

  const float* ap = A + (size_t)row*64 + kb0;
  half8v af0, af1;
  #pragma unroll
  for (int u = 0; u < 8; u++) {
    int k0i = kb0 + u, k1i = 32 + kb0 + u;
    float m0 = bns1[k0i]*invN, m1 = bns1[k1i]*invN;
    float va0 = bns2[k0i]*invN - m0*m0, va1 = bns2[k1i]*invN - m1*m1;
    af0[u] = (f16)((ap[u]    - m0)*rsqrtf(va0+BN_EPS)*g[k0i] + b[k0i]);
    af1[u] = (f16)((ap[32+u] - m1)*rsqrtf(va1+BN_EPS)*g[k1i] + b[k1i]);
  }
  f32x4 acc1[8] = {{0,0,0,0},{0,0,0,0},{0,0,0,0},{0,0,0,0},
                   {0,0,0,0},{0,0,0,0},{0,0,0,0},{0,0,0,0}};
  #pragma unroll
  for (int jf = 0; jf < 8; jf++) {
    const f16* wp = W1 + (size_t)(jf*16 + (lane & 15))*64 + kb0;
    acc1[jf] = __builtin_amdgcn_mfma_f32_16x16x32_f16(af0, *(const half8v*)wp, acc1[jf], 0, 0, 0);
    acc1[jf] = __builtin_amdgcn_mfma_f32_16x16x32_f16(af1, *(const half8v*)(wp+32), acc1[jf], 0, 0, 0);
  }
  #pragma unroll
  for (int jf = 0; jf < 8; jf++) {
    int col = jf*16 + (lane & 15);
    float bv = b1v[col];
    #pragma unroll
    for (int r = 0; r < 4; r++) {
      int rl = ((lane >> 4) << 2) + r;
      y1s[wv][rl][col] = (f16)rrelu(acc1[jf][r] + bv);
    }
  }
  __syncthreads();
  half8v bf[4];
  #pragma unroll
  for (int q = 0; q < 4; q++)
    bf[q] = *(const half8v*)&y1s[wv][lane & 15][q*32 + kb0];
  f32x4 acc2[8] = {{0,0,0,0},{0,0,0,0},{0,0,0,0},{0,0,0,0},
                   {0,0,0,0},{0,0,0,0},{0,0,0,0},{0,0,0,0}};
  #pragma unroll
  for (int jf = 0; jf < 8; jf++) {
    const f16* wp = W2 + (size_t)(jf*16 + (lane & 15))*128 + kb0;
    #pragma unroll
    for (int q = 0; q < 4; q++)
      acc2[jf] = __builtin_amdgcn_mfma_f32_16x16x32_f16(bf[q], *(const half8v*)(wp + q*32), acc2[jf], 0, 0, 0);
  }
  int r0 = n0 + ((lane >> 4) << 2);
  #pragma unroll
  for (int jf = 0; jf < 8; jf++) {
    int col = jf*16 + (lane & 15);
    float bv = b2v[col];
    #pragma unroll
    for (int r = 0; r < 4; r++)
      outB[(size_t)(r0 + r)*128 + col] = rrelu(acc2[jf][r] + bv);
  }
}

// ================= small kernels =================
// merged node-embed + edge-embed + cnt atomics + sA1 zero-tail
__global__ void embed_k(const float* __restrict__ x,
                        const float* __restrict__ mean, const float* __restrict__ var,
                        const float* __restrict__ g, const float* __restrict__ b,
                        const float* __restrict__ Wn, const float* __restrict__ bnode,
                        float* __restrict__ nodeA,
                        const float* __restrict__ eattr,
                        const float* __restrict__ We, const float* __restrict__ be,
                        float* __restrict__ ea12,
                        const int* __restrict__ ei, const int* __restrict__ ei3,
                        float* __restrict__ cnt1, float* __restrict__ cnt2,
                        float* __restrict__ zptr) {
  int bid = blockIdx.x, t = threadIdx.x;
  if (bid < 2048) {
    int idx = bid * 256 + t;
    int n = idx >> 6, o = idx & 63;
    float acc = bnode[o];
    #pragma unroll
    for (int i = 0; i < 8; i++) {
      float xn = (x[n*8+i] - mean[i]) * rsqrtf(var[i] + BN_EPS) * g[i] + b[i];
      acc += xn * Wn[i*64 + o];
    }
    nodeA[idx] = rrelu(acc);
  } else if (bid < 2816) {
    int idx = (bid - 2048) * 256 + t;
    if (idx >= N_EDGES * 12) return;
    int e = idx / 12, j = idx - e * 12;
    float acc = be[j];
    #pragma unroll
    for (int k = 0; k < 19; k++) acc += eattr[e*19+k] * We[k*12 + j];
    ea12[idx] = rrelu(acc);
  } else if (bid < 2880) {
    int idx = (bid - 2816) * 256 + t;
    if (idx < N_EDGES) atomicAdd(&cnt1[ei[N_EDGES + idx]], 1.0f);
    if (idx < N_E3) {
      atomicAdd(&cnt2[ei3[N_E3 + idx]], 1.0f);
      atomicAdd(&cnt2[ei3[idx]], 1.0f);
    }
  } else {
    zero_tail(bid - 2880, zptr, N_NODES*64);
  }
}

// packs: f16 weights [J,K] + fp32 Wfold + zero cnt/bns + x-BN-stats (blocks 512..519, one per feature)
__global__ void pack_k(const float* __restrict__ Wnn1,
                       const float* __restrict__ Wih1, const float* __restrict__ Whh1,
                       const float* __restrict__ Wc1,  const float* __restrict__ Wc2,
                       const float* __restrict__ Wnn2,
                       const float* __restrict__ Wih2, const float* __restrict__ Whh2,
                       const float* __restrict__ Ws_ih, const float* __restrict__ Ws_hh,
                       const float* __restrict__ x,
                       f16* __restrict__ Wz1h,
                       f16* __restrict__ Wih1h, f16* __restrict__ Whh1h,
                       f16* __restrict__ Wc1Th, f16* __restrict__ Wc2Th,
                       f16* __restrict__ W2fh,
                       f16* __restrict__ Wih2h, f16* __restrict__ Whh2h,
                       float* __restrict__ Wfold,
                       float* __restrict__ cnt1, float* __restrict__ cnt2,
                       float* __restrict__ bns1, float* __restrict__ bns2,
                       float* __restrict__ mean, float* __restrict__ var) {
  if (blockIdx.x >= 512) {
    // x-stats: one block per feature, 256 threads x 32 rows + LDS tree (R9 bn_stats shape)
    int f = blockIdx.x - 512, t = threadIdx.x;
    __shared__ float s1[256], s2[256];
    float a = 0.f, bq = 0.f;
    for (int n = t; n < N_NODES; n += 256) {
      float v = x[n*8 + f];
      a += v; bq += v*v;
    }
    s1[t] = a; s2[t] = bq; __syncthreads();
    for (int w = 128; w > 0; w >>= 1) {
      if (t < w) { s1[t] += s1[t+w]; s2[t] += s2[t+w]; }
      __syncthreads();
    }
    if (t == 0) {
      float m = s1[0] / (float)N_NODES;
      mean[f] = m;
      var[f]  = s2[0] / (float)N_NODES - m*m;
    }
    return;
  }
  int idx = blockIdx.x * 256 + threadIdx.x;
  if (idx < 49152) {
    int jj = idx >> 6, i = idx & 63;
    int k = jj >> 6, o = jj & 63;
    Wz1h[idx] = (f16)Wnn1[k*4096 + i*64 + o];
  }
  if (idx < 12288) { Wih1h[idx] = (f16)Wih1[idx]; Whh1h[idx] = (f16)Whh1[idx]; }
  if (idx < 8192) {
    int o = idx >> 6, i = idx & 63;
    Wc1Th[idx] = (f16)Wc1[i*128 + o];
  }
  if (idx < 16384) {
    int o = idx >> 7, i = idx & 127;
    Wc2Th[idx] = (f16)Wc2[i*128 + o];
  }
  if (idx < 131072) {
    int r = idx >> 7, i = idx & 127;
    int k = r >> 7, o = r & 127;
    W2fh[idx] = (f16)Wnn2[k*16384 + i*128 + o];
  }
  if (idx < 49152) { Wih2h[idx] = (f16)Wih2[idx]; Whh2h[idx] = (f16)Whh2[idx]; }
  if (idx < 131072) {
    int i = idx >> 9, j = idx & 511;
    float v = Ws_ih[(size_t)j*256 + i];
    if (i < 128) v += Ws_hh[(size_t)j*128 + i];
    Wfold[idx] = v;
  }
  if (idx < N_NODES) { cnt1[idx] = 0.f; cnt2[idx] = 0.f; }
  if (idx < 128) { bns1[idx] = 0.f; bns2[idx] = 0.f; }
}

// ---------- Set2Set ----------
__global__ __launch_bounds__(1024) void set2set_k(const float* __restrict__ x,
    const float* __restrict__ Wfold,
    const float* __restrict__ bs_ih, const float* __restrict__ bs_hh,
    float* __restrict__ qpool) {
  int g = blockIdx.x, t = threadIdx.x;
  __shared__ float xs[NPG*128];
  __shared__ float hr[256];
  __shared__ float cbuf[128];
  __shared__ float pbuf[1024];
  __shared__ float abuf[NPG];
  *(float4*)&xs[t*4] = *(const float4*)(x + (size_t)g*NPG*128 + t*4);
  if (t < 128) {
    float gi = bs_ih[t]     + bs_hh[t];
    float gg = bs_ih[256+t] + bs_hh[256+t];
    float go = bs_ih[384+t] + bs_hh[384+t];
    float c0 = sigm(gi) * tanhf(gg);
    cbuf[t] = c0;
    hr[t] = sigm(go) * tanhf(c0);
  }
  __syncthreads();
  #pragma unroll 1
  for (int step = 0; step < 3; step++) {
    {
      int node = t >> 5, s = t & 31;
      const float* xr = xs + node*128 + s*4;
      float pv = xr[0]*hr[s*4] + xr[1]*hr[s*4+1] + xr[2]*hr[s*4+2] + xr[3]*hr[s*4+3];
      pv += __shfl_down(pv, 16, 32); pv += __shfl_down(pv, 8, 32);
      pv += __shfl_down(pv, 4, 32);  pv += __shfl_down(pv, 2, 32);
      pv += __shfl_down(pv, 1, 32);
      if (s == 0) pbuf[node] = pv;
    }
    __syncthreads();
    if (t < NPG) {
      float e = pbuf[t];
      float mx = e;
      for (int o = 16; o > 0; o >>= 1) mx = fmaxf(mx, __shfl_xor(mx, o, 32));
      float ex = __expf(e - mx);
      float den = ex;
      for (int o = 16; o > 0; o >>= 1) den += __shfl_xor(den, o, 32);
      abuf[t] = ex / den;
    }
    __syncthreads();
    if (t < 128) {
      float r = 0.f;
      #pragma unroll 8
      for (int nn = 0; nn < NPG; nn++) r += abuf[nn] * xs[nn*128 + t];
      hr[128 + t] = r;
    }
    __syncthreads();
    if (step == 2) break;
    {
      int j = t & 511, half = t >> 9;
      const float* wp = Wfold + (size_t)(half*128)*512 + j;
      const float* iv = hr + half*128;
      float a0=0.f, a1=0.f, a2=0.f, a3=0.f;
      #pragma unroll 4
      for (int i = 0; i < 128; i += 4) {
        a0 += iv[i]   * wp[(i)  *512];
        a1 += iv[i+1] * wp[(i+1)*512];
        a2 += iv[i+2] * wp[(i+2)*512];
        a3 += iv[i+3] * wp[(i+3)*512];
      }
      pbuf[t] = a0 + a1 + a2 + a3;
    }
    __syncthreads();
    if (t < 128) {
      float gi = pbuf[t]     + pbuf[512+t] + bs_ih[t]     + bs_hh[t];
      float gf = pbuf[128+t] + pbuf[640+t] + bs_ih[128+t] + bs_hh[128+t];
      float gg = pbuf[256+t] + pbuf[768+t] + bs_ih[256+t] + bs_hh[256+t];
      float go = pbuf[384+t] + pbuf[896+t] + bs_ih[384+t] + bs_hh[384+t];
      float ci = sigm(gf) * cbuf[t] + sigm(gi) * tanhf(gg);
      cbuf[t] = ci;
      hr[t] = sigm(go) * tanhf(ci);
    }
    __syncthreads();
  }
  if (t < 256) qpool[g*256 + t] = hr[t];
}

// ======== yhat + per-column BN stats fused: one wave per column ========
__global__ __launch_bounds__(256) void ys_k(const float* __restrict__ feat,
    const int* __restrict__ ei3, const int* __restrict__ batch,
    const float* __restrict__ qpool,
    float* __restrict__ yhat, float* __restrict__ mean, float* __restrict__ var) {
  int t = threadIdx.x, lane = t & 63, wv = t >> 6;
  int j = blockIdx.x*4 + wv;          // 160 blocks * 4 waves = 640 columns
  float s = 0.f, q = 0.f;
  for (int e = lane; e < N_E3; e += 64) {
    int s0 = ei3[e], s1 = ei3[N_E3 + e];
    float v;
    if (j < 128)      { v = 0.5f * (feat[s0*128+j] + feat[s1*128+j]); }
    else if (j < 256) { int jj = j-128; v = feat[s0*128+jj] * feat[s1*128+jj]; }
    else if (j < 384) { int jj = j-256; float d = feat[s0*128+jj] - feat[s1*128+jj]; v = d*d; }
    else              { int cbi = batch[s0]; v = qpool[cbi*256 + (j-384)]; }
    yhat[(size_t)e*640 + j] = v;
    s += v; q += v*v;
  }
  #pragma unroll
  for (int o = 32; o > 0; o >>= 1) { s += __shfl_xor(s, o); q += __shfl_xor(q, o); }
  if (lane == 0) {
    float m = s / (float)N_E3;
    mean[j] = m;
    var[j]  = q / (float)N_E3 - m*m;
  }
}

__global__ void final_k(const float* __restrict__ yhat,
                        const float* __restrict__ mean, const float* __restrict__ var,
                        const float* __restrict__ g, const float* __restrict__ b,
                        const float* __restrict__ ea3,
                        const float* __restrict__ Ww, const float* __restrict__ Wb,
                        float* __restrict__ out) {
  int e = blockIdx.x, t = threadIdx.x;
  __shared__ float red[128];
  float av[8];
  #pragma unroll
  for (int k = 0; k < 8; k++) av[k] = ea3[e*8 + k];
  float acc = 0.f;
  for (int j = t; j < 640; j += 128) {
    float yn = (yhat[(size_t)e*640 + j] - mean[j]) * rsqrtf(var[j] + BN_EPS) * g[j] + b[j];
    float wj = 0.f;
    #pragma unroll
    for (int k = 0; k < 8; k++) wj += av[k] * Ww[k*640 + j];
    acc += yn * wj;
  }
  red[t] = acc; __syncthreads();
  for (int w = 64; w > 0; w >>= 1) {
    if (t < w) red[t] += red[t+w];
    __syncthreads();
  }
  if (t == 0) {
    float bb = 0.f;
    #pragma unroll
    for (int k = 0; k < 8; k++) bb += av[k] * Wb[k];
    out[e] = red[0] + bb;
  }
}

extern "C" void kernel_launch(void* const* d_in, const int* in_sizes, int n_in,
                              void* d_out, int out_size, void* d_ws, size_t ws_size,
                              hipStream_t stream) {
  const float* x      = (const float*)d_in[0];
  const int*   ei     = (const int*)  d_in[1];
  const float* eattr  = (const float*)d_in[2];
  const int*   ei3    = (const int*)  d_in[3];
  const float* ea3    = (const float*)d_in[4];
  const int*   batch  = (const int*)  d_in[5];
  const float* bnx_g  = (const float*)d_in[6];
  const float* bnx_b  = (const float*)d_in[7];
  const float* Wn     = (const float*)d_in[8];
  const float* bnode  = (const float*)d_in[9];
  const float* We     = (const float*)d_in[10];
  const float* be     = (const float*)d_in[11];
  const float* Wnn1   = (const float*)d_in[12];
  const float* bias1  = (const float*)d_in[13];
  const float* Wih1   = (const float*)d_in[14];
  const float* Whh1   = (const float*)d_in[15];
  const float* bih1   = (const float*)d_in[16];
  const float* bhh1   = (const float*)d_in[17];
  const float* bnc_g  = (const float*)d_in[18];
  const float* bnc_b  = (const float*)d_in[19];
  const float* Wc1    = (const float*)d_in[20];
  const float* bc1    = (const float*)d_in[21];
  const float* Wc2    = (const float*)d_in[22];
  const float* bc2    = (const float*)d_in[23];
  const float* Wnn2   = (const float*)d_in[24];
  const float* bias2  = (const float*)d_in[25];
  const float* Wih2   = (const float*)d_in[26];
  const float* Whh2   = (const float*)d_in[27];
  const float* bih2   = (const float*)d_in[28];
  const float* bhh2   = (const float*)d_in[29];
  const float* Ws_ih  = (const float*)d_in[30];
  const float* Ws_hh  = (const float*)d_in[31];
  const float* bs_ih  = (const float*)d_in[32];
  const float* bs_hh  = (const float*)d_in[33];
  const float* bno_g  = (const float*)d_in[34];
  const float* bno_b  = (const float*)d_in[35];
  const float* Ww     = (const float*)d_in[36];
  const float* Wb     = (const float*)d_in[37];
  float* out = (float*)d_out;

  // workspace carve-up
  float* W = (float*)d_ws;
  size_t off = 0;
  float* Wfold  = W + off; off += 131072;
  float* ea12   = W + off; off += (size_t)N_EDGES * 12;
  float* nodeA  = W + off; off += (size_t)N_NODES * 64;
  float* nodeA2 = W + off; off += (size_t)N_NODES * 64;
  float* sA1    = W + off; off += (size_t)N_NODES * 64;
  float* sA2    = W + off; off += (size_t)N_NODES * 64;
  float* sB1    = W + off; off += (size_t)N_NODES * 128;
  float* sB2    = W + off; off += (size_t)N_NODES * 128;
  float* cnt1   = W + off; off += (size_t)N_NODES;
  float* cnt2   = W + off; off += (size_t)N_NODES;
  float* nodeB  = W + off; off += (size_t)N_NODES * 128;
  float* nodeB2 = W + off; off += (size_t)N_NODES * 128;
  float* qpool  = W + off; off += (size_t)NGRAPH * 256;
  float* yhat   = W + off; off += (size_t)N_E3 * 640;
  float* mean   = W + off; off += 640;
  float* var    = W + off; off += 640;
  float* bns1   = W + off; off += 128;
  float* bns2   = W + off; off += 128;
  f16* F = (f16*)(W + off);
  size_t foff = 0;
  f16* Wz1h  = F + foff; foff += 49152;
  f16* Wih1h = F + foff; foff += 12288;
  f16* Whh1h = F + foff; foff += 12288;
  f16* Wc1Th = F + foff; foff += 8192;
  f16* Wc2Th = F + foff; foff += 16384;
  f16* W2fh  = F + foff; foff += 131072;
  f16* Wih2h = F + foff; foff += 49152;
  f16* Whh2h = F + foff; foff += 49152;
  (void)foff; (void)ws_size; (void)in_sizes; (void)n_in; (void)out_size;

  // 1. pack (+zero cnt/bns, +x-stats blocks 512..519)
  pack_k<<<520, 256, 0, stream>>>(Wnn1, Wih1, Whh1, Wc1, Wc2, Wnn2, Wih2, Whh2, Ws_ih, Ws_hh, x,
                                  Wz1h, Wih1h, Whh1h, Wc1Th, Wc2Th, W2fh, Wih2h, Whh2h,
                                  Wfold, cnt1, cnt2, bns1, bns2, mean, var);
  // 2. embeds (+cnt atomics, +zero sA1)
  embed_k<<<2896, 256, 0, stream>>>(x, mean, var, bnx_g, bnx_b, Wn, bnode, nodeA,
                                    eattr, We, be, ea12, ei, ei3, cnt1, cnt2, sA1);

  // 3-6. layer-1 x2 (ping-pong h and sbuf)
  conv1f_k<<<256, 256, 0, stream>>>(nodeA, ei, ea12, Wz1h, sA1);
  gruf_k<6,0><<<272, 128, 0, stream>>>(sA1, cnt1, bias1, Wih1h, Whh1h, bih1, bhh1,
                                       nodeA, nodeA2, nullptr, nullptr,
                                       256, sA2, N_NODES*64);
  conv1f_k<<<256, 256, 0, stream>>>(nodeA2, ei, ea12, Wz1h, sA2);
  gruf_k<6,1><<<272, 128, 0, stream>>>(sA2, cnt1, bias1, Wih1h, Whh1h, bih1, bhh1,
                                       nodeA2, nodeA, bns1, bns2,
                                       256, sB1, N_NODES*128);

  // 7. fused BN + FC1 + FC2 (+zero sB2)
  fcf_k<<<144, 256, 0, stream>>>(nodeA, Wc1Th, bc1, Wc2Th, bc2,
                                 bns1, bns2, bnc_g, bnc_b, nodeB,
                                 128, sB2, N_NODES*128);

  // 8-11. layer-2 x2
  conv2f_k<<<256, 512, 0, stream>>>(nodeB, ei3, ea3, W2fh, sB1);
  gruf_k<7,0><<<256, 256, 0, stream>>>(sB1, cnt2, bias2, Wih2h, Whh2h, bih2, bhh2,
                                       nodeB, nodeB2, nullptr, nullptr,
                                       256, nullptr, 0);
  conv2f_k<<<256, 512, 0, stream>>>(nodeB2, ei3, ea3, W2fh, sB2);
  gruf_k<7,0><<<256, 256, 0, stream>>>(sB2, cnt2, bias2, Wih2h, Whh2h, bih2, bhh2,
                                       nodeB2, nodeB, nullptr, nullptr,
                                       256, nullptr, 0);

  // 12. set2set
  set2set_k<<<NGRAPH, 1024, 0, stream>>>(nodeB, Wfold, bs_ih, bs_hh, qpool);

  // 13. yhat + column stats (fused)
  ys_k<<<160, 256, 0, stream>>>(nodeB, ei3, batch, qpool, yhat, mean, var);

  // 14. weighted sum
  final_k<<<N_E3, 128, 0, stream>>>(yhat, mean, var, bno_g, bno_b, ea3, Ww, Wb, out);
}

// Round 13
// 196.629 us; speedup vs baseline: 2.7401x; 1.0228x over previous
//
#include <hip/hip_runtime.h>
#include <hip/hip_bf16.h>
#include <math.h>

#define N_NODES 8192
#define N_EDGES 16384
#define N_E3    1024
#define NGRAPH  256
#define NPG     32
#define SLOPE   (11.0f/48.0f)
#define BN_EPS  1e-5f

__device__ __forceinline__ float rrelu(float v){ return v >= 0.f ? v : SLOPE*v; }
__device__ __forceinline__ float sigm(float v){ return 1.f/(1.f+__expf(-v)); }

typedef _Float16 f16;
typedef __attribute__((ext_vector_type(8))) _Float16 half8v;
typedef __attribute__((ext_vector_type(4))) float f32x4;

__device__ __forceinline__ void zero_tail(int zb, float* zptr, int zcount) {
  float4 z4 = make_float4(0.f,0.f,0.f,0.f);
  int bd = blockDim.x;
  for (int i = zb*bd + (int)threadIdx.x; i*4 < zcount; i += 16*bd)
    ((float4*)zptr)[i] = z4;
}

// ======== conv1 fused: msg[e,o] = sum_kg ea[e,kg]*(nodeA[src[e]] @ W_kg)[o], atomic scatter
__global__ __launch_bounds__(256) void conv1f_k(const float* __restrict__ nodeA,
    const int* __restrict__ ei, const float* __restrict__ ea,
    const f16* __restrict__ Wz1h, float* __restrict__ sbuf) {
  int t = threadIdx.x, lane = t & 63, wv = t >> 6;
  int e0 = blockIdx.x*64 + wv*16;
  int eA = e0 + (lane & 15);
  int src = ei[eA];
  int kb0 = (lane >> 4) * 8;
  const float* ap = nodeA + (size_t)src*64 + kb0;
  float4 v0 = *(const float4*)ap,      v1 = *(const float4*)(ap+4);
  float4 v2 = *(const float4*)(ap+32), v3 = *(const float4*)(ap+36);
  half8v a0, a1;
  a0[0]=(f16)v0.x; a0[1]=(f16)v0.y; a0[2]=(f16)v0.z; a0[3]=(f16)v0.w;
  a0[4]=(f16)v1.x; a0[5]=(f16)v1.y; a0[6]=(f16)v1.z; a0[7]=(f16)v1.w;
  a1[0]=(f16)v2.x; a1[1]=(f16)v2.y; a1[2]=(f16)v2.z; a1[3]=(f16)v2.w;
  a1[4]=(f16)v3.x; a1[5]=(f16)v3.y; a1[6]=(f16)v3.z; a1[7]=(f16)v3.w;
  float eav[12];
  #pragma unroll
  for (int kg = 0; kg < 12; kg++) eav[kg] = ea[eA*12 + kg];

  f32x4 acc[4] = {{0,0,0,0},{0,0,0,0},{0,0,0,0},{0,0,0,0}};
  #pragma unroll
  for (int kg = 0; kg < 12; kg++) {
    f16 s = (f16)eav[kg];
    half8v s0, s1;
    #pragma unroll
    for (int u = 0; u < 8; u++) { s0[u] = a0[u]*s; s1[u] = a1[u]*s; }
    #pragma unroll
    for (int jf = 0; jf < 4; jf++) {
      const f16* wp = Wz1h + (size_t)(kg*64 + jf*16 + (lane & 15))*64 + kb0;
      acc[jf] = __builtin_amdgcn_mfma_f32_16x16x32_f16(s0, *(const half8v*)wp, acc[jf], 0, 0, 0);
      acc[jf] = __builtin_amdgcn_mfma_f32_16x16x32_f16(s1, *(const half8v*)(wp+32), acc[jf], 0, 0, 0);
    }
  }
  int dstv[4];
  #pragma unroll
  for (int r = 0; r < 4; r++) dstv[r] = ei[N_EDGES + e0 + ((lane>>4)<<2) + r];
  #pragma unroll
  for (int jf = 0; jf < 4; jf++) {
    int col = jf*16 + (lane & 15);
    #pragma unroll
    for (int r = 0; r < 4; r++)
      atomicAdd(&sbuf[dstv[r]*64 + col], acc[jf][r]);
  }
}

// ======== conv2 fused, parallelized: 256 blocks x 512 thr ========
__global__ __launch_bounds__(512) void conv2f_k(const float* __restrict__ nodeB,
    const int* __restrict__ ei3, const float* __restrict__ ea3,
    const f16* __restrict__ W2fh, float* __restrict__ sbuf) {
  int t = threadIdx.x, lane = t & 63, wv = t >> 6;
  int eg = blockIdx.x >> 1, qh = blockIdx.x & 1;
  int kgh = wv >> 2, jp = wv & 3;
  int e0 = eg * 16;
  int eA = e0 + (lane & 15);
  int src = ei3[eA];
  int kb0 = qh*64 + (lane >> 4) * 8;
  const float* ap = nodeB + (size_t)src*128 + kb0;
  half8v a0, a1;
  {
    float4 w0 = *(const float4*)ap,        w1 = *(const float4*)(ap+4);
    float4 w2 = *(const float4*)(ap + 32), w3 = *(const float4*)(ap+36);
    a0[0]=(f16)w0.x; a0[1]=(f16)w0.y; a0[2]=(f16)w0.z; a0[3]=(f16)w0.w;
    a0[4]=(f16)w1.x; a0[5]=(f16)w1.y; a0[6]=(f16)w1.z; a0[7]=(f16)w1.w;
    a1[0]=(f16)w2.x; a1[1]=(f16)w2.y; a1[2]=(f16)w2.z; a1[3]=(f16)w2.w;
    a1[4]=(f16)w3.x; a1[5]=(f16)w3.y; a1[6]=(f16)w3.z; a1[7]=(f16)w3.w;
  }
  int eb = eA & (N_E3 - 1);
  float eav[4];
  #pragma unroll
  for (int kk = 0; kk < 4; kk++) eav[kk] = ea3[eb*8 + kgh*4 + kk];

  f32x4 acc[2] = {{0,0,0,0},{0,0,0,0}};
  #pragma unroll
  for (int kk = 0; kk < 4; kk++) {
    f16 s = (f16)eav[kk];
    half8v s0, s1;
    #pragma unroll
    for (int u = 0; u < 8; u++) { s0[u] = a0[u]*s; s1[u] = a1[u]*s; }
    int kg = kgh*4 + kk;
    #pragma unroll
    for (int jj = 0; jj < 2; jj++) {
      int jf = jp*2 + jj;
      const f16* wp = W2fh + (size_t)(kg*128 + jf*16 + (lane & 15))*128 + kb0;
      acc[jj] = __builtin_amdgcn_mfma_f32_16x16x32_f16(s0, *(const half8v*)wp, acc[jj], 0, 0, 0);
      acc[jj] = __builtin_amdgcn_mfma_f32_16x16x32_f16(s1, *(const half8v*)(wp+32), acc[jj], 0, 0, 0);
    }
  }
  int dstv[4];
  #pragma unroll
  for (int r = 0; r < 4; r++) dstv[r] = ei3[(e0 + ((lane>>4)<<2) + r + N_E3) & (2*N_E3 - 1)];
  #pragma unroll
  for (int jj = 0; jj < 2; jj++) {
    int col = (jp*2+jj)*16 + (lane & 15);
    #pragma unroll
    for (int r = 0; r < 4; r++)
      atomicAdd(&sbuf[dstv[r]*128 + col], acc[jj][r]);
  }
}

// ======== fused GRU ========
template<int LOGH, int STATS>
__global__ void gruf_k(const float* __restrict__ sbuf, const float* __restrict__ cnt,
                       const float* __restrict__ mbias,
                       const f16* __restrict__ Wih, const f16* __restrict__ Whh,
                       const float* __restrict__ bih, const float* __restrict__ bhh,
                       const float* __restrict__ hold, float* __restrict__ hnew,
                       float* __restrict__ bns1, float* __restrict__ bns2,
                       int nblk, float* __restrict__ zptr, int zcount) {
  if ((int)blockIdx.x >= nblk) { zero_tail(blockIdx.x - nblk, zptr, zcount); return; }
  const int H = 1 << LOGH;
  const int K = H;
  const int jt = H >> 6;
  int t = threadIdx.x;
  int lane = t & 63, wv = t >> 6;
  int wpb = blockDim.x >> 6;
  int bm = blockIdx.x / jt, bj = blockIdx.x % jt;
  int n0 = bm * (wpb << 4) + (wv << 4);
  int j0 = bj << 6;
  int row = n0 + (lane & 15);
  int kb0 = (lane >> 4) * 8;

  f32x4 aR[4]  = {{0,0,0,0},{0,0,0,0},{0,0,0,0},{0,0,0,0}};
  f32x4 aZ[4]  = {{0,0,0,0},{0,0,0,0},{0,0,0,0},{0,0,0,0}};
  f32x4 aIN[4] = {{0,0,0,0},{0,0,0,0},{0,0,0,0},{0,0,0,0}};
  f32x4 aHN[4] = {{0,0,0,0},{0,0,0,0},{0,0,0,0},{0,0,0,0}};

  float dn = 1.f / fmaxf(cnt[row], 1.0f);
  for (int k0 = 0; k0 < K; k0 += 32) {
    int kb = k0 + kb0;
    const float* ap = sbuf + (size_t)row * K + kb;
    float4 v0 = *(const float4*)ap, v1 = *(const float4*)(ap + 4);
    float4 b0 = *(const float4*)(mbias + kb), b1 = *(const float4*)(mbias + kb + 4);
    half8v af;
    af[0]=(f16)rrelu(v0.x*dn+b0.x); af[1]=(f16)rrelu(v0.y*dn+b0.y);
    af[2]=(f16)rrelu(v0.z*dn+b0.z); af[3]=(f16)rrelu(v0.w*dn+b0.w);
    af[4]=(f16)rrelu(v1.x*dn+b1.x); af[5]=(f16)rrelu(v1.y*dn+b1.y);
    af[6]=(f16)rrelu(v1.z*dn+b1.z); af[7]=(f16)rrelu(v1.w*dn+b1.w);
    #pragma unroll
    for (int jf = 0; jf < 4; jf++) {
      int wr = j0 + jf*16 + (lane & 15);
      half8v wR = *(const half8v*)(Wih + (size_t)wr*K + kb);
      half8v wZ = *(const half8v*)(Wih + (size_t)(H + wr)*K + kb);
      half8v wN = *(const half8v*)(Wih + (size_t)(2*H + wr)*K + kb);
      aR[jf]  = __builtin_amdgcn_mfma_f32_16x16x32_f16(af, wR, aR[jf], 0, 0, 0);
      aZ[jf]  = __builtin_amdgcn_mfma_f32_16x16x32_f16(af, wZ, aZ[jf], 0, 0, 0);
      aIN[jf] = __builtin_amdgcn_mfma_f32_16x16x32_f16(af, wN, aIN[jf], 0, 0, 0);
    }
  }
  for (int k0 = 0; k0 < K; k0 += 32) {
    int kb = k0 + kb0;
    const float* ap = hold + (size_t)row * K + kb;
    float4 v0 = *(const float4*)ap, v1 = *(const float4*)(ap + 4);
    half8v af;
    af[0]=(f16)v0.x; af[1]=(f16)v0.y; af[2]=(f16)v0.z; af[3]=(f16)v0.w;
    af[4]=(f16)v1.x; af[5]=(f16)v1.y; af[6]=(f16)v1.z; af[7]=(f16)v1.w;
    #pragma unroll
    for (int jf = 0; jf < 4; jf++) {
      int wr = j0 + jf*16 + (lane & 15);
      half8v wR = *(const half8v*)(Whh + (size_t)wr*K + kb);
      half8v wZ = *(const half8v*)(Whh + (size_t)(H + wr)*K + kb);
      half8v wN = *(const half8v*)(Whh + (size_t)(2*H + wr)*K + kb);
      aR[jf]  = __builtin_amdgcn_mfma_f32_16x16x32_f16(af, wR, aR[jf], 0, 0, 0);
      aZ[jf]  = __builtin_amdgcn_mfma_f32_16x16x32_f16(af, wZ, aZ[jf], 0, 0, 0);
      aHN[jf] = __builtin_amdgcn_mfma_f32_16x16x32_f16(af, wN, aHN[jf], 0, 0, 0);
    }
  }
  int r0 = n0 + ((lane >> 4) << 2);
  #pragma unroll
  for (int jf = 0; jf < 4; jf++) {
    int col = j0 + jf*16 + (lane & 15);
    float bR = bih[col] + bhh[col];
    float bZ = bih[H + col] + bhh[H + col];
    float bI = bih[2*H + col], bH = bhh[2*H + col];
    float ssum = 0.f, sq = 0.f;
    #pragma unroll
    for (int r = 0; r < 4; r++) {
      float rr = sigm(aR[jf][r] + bR);
      float zz = sigm(aZ[jf][r] + bZ);
      float nn = tanhf(aIN[jf][r] + bI + rr*(aHN[jf][r] + bH));
      float ho = hold[(size_t)(r0 + r)*H + col];
      float hv = (1.f - zz)*nn + zz*ho;
      hnew[(size_t)(r0 + r)*H + col] = hv;
      if (STATS) { ssum += hv; sq += hv*hv; }
    }
    if (STATS) {
      ssum += __shfl_xor(ssum, 16); ssum += __shfl_xor(ssum, 32);
      sq   += __shfl_xor(sq, 16);   sq   += __shfl_xor(sq, 32);
      if (lane < 16) { atomicAdd(&bns1[col], ssum); atomicAdd(&bns2[col], sq); }
    }
  }
}

// ======== fused FC1+FC2 ========
__global__ __launch_bounds__(256) void fcf_k(const float* __restrict__ A,
    const f16* __restrict__ W1, const float* __restrict__ b1v,
    const f16* __restrict__ W2, const float* __restrict__ b2v,
    const float* __restrict__ bns1, const float* __restrict__ bns2,
    const float* __restrict__ g, const float* __restrict__ b,
    float* __restrict__ outB,
    int nblk, float* __restrict__ zptr, int zcount) {
  if ((int)blockIdx.x >= nblk) { zero_tail(blockIdx.x - nblk, zptr, zcount); return; }
  __shared__ f16 y1s[4][16][128];
  int t = threadIdx.x, lane = t & 63, wv = t >> 6;
  int n0 = blockIdx.x*64 + wv*16;
  int row = n0 + (lane & 15);
  int kb0 = (lane >> 4) * 8;
  const float invN = 1.f / (float)N_NODES;

  const float* ap = A + (size_t)row*64 + kb0;
  half8v af0, af1;
  #pragma unroll
  for (int u = 0; u < 8; u++) {
    int k0i = kb0 + u, k1i = 32 + kb0 + u;
    float m0 = bns1[k0i]*invN, m1 = bns1[k1i]*invN;
    float va0 = bns2[k0i]*invN - m0*m0, va1 = bns2[k1i]*invN - m1*m1;
    af0[u] = (f16)((ap[u]    - m0)*rsqrtf(va0+BN_EPS)*g[k0i] + b[k0i]);
    af1[u] = (f16)((ap[32+u] - m1)*rsqrtf(va1+BN_EPS)*g[k1i] + b[k1i]);
  }
  f32x4 acc1[8] = {{0,0,0,0},{0,0,0,0},{0,0,0,0},{0,0,0,0},
                   {0,0,0,0},{0,0,0,0},{0,0,0,0},{0,0,0,0}};
  #pragma unroll
  for (int jf = 0; jf < 8; jf++) {
    const f16* wp = W1 + (size_t)(jf*16 + (lane & 15))*64 + kb0;
    acc1[jf] = __builtin_amdgcn_mfma_f32_16x16x32_f16(af0, *(const half8v*)wp, acc1[jf], 0, 0, 0);
    acc1[jf] = __builtin_amdgcn_mfma_f32_16x16x32_f16(af1, *(const half8v*)(wp+32), acc1[jf], 0, 0, 0);
  }
  #pragma unroll
  for (int jf = 0; jf < 8; jf++) {
    int col = jf*16 + (lane & 15);
    float bv = b1v[col];
    #pragma unroll
    for (int r = 0; r < 4; r++) {
      int rl = ((lane >> 4) << 2) + r;
      y1s[wv][rl][col] = (f16)rrelu(acc1[jf][r] + bv);
    }
  }
  __syncthreads();
  half8v bf[4];
  #pragma unroll
  for (int q = 0; q < 4; q++)
    bf[q] = *(const half8v*)&y1s[wv][lane & 15][q*32 + kb0];
  f32x4 acc2[8] = {{0,0,0,0},{0,0,0,0},{0,0,0,0},{0,0,0,0},
                   {0,0,0,0},{0,0,0,0},{0,0,0,0},{0,0,0,0}};
  #pragma unroll
  for (int jf = 0; jf < 8; jf++) {
    const f16* wp = W2 + (size_t)(jf*16 + (lane & 15))*128 + kb0;
    #pragma unroll
    for (int q = 0; q < 4; q++)
      acc2[jf] = __builtin_amdgcn_mfma_f32_16x16x32_f16(bf[q], *(const half8v*)(wp + q*32), acc2[jf], 0, 0, 0);
  }
  int r0 = n0 + ((lane >> 4) << 2);
  #pragma unroll
  for (int jf = 0; jf < 8; jf++) {
    int col = jf*16 + (lane & 15);
    float bv = b2v[col];
    #pragma unroll
    for (int r = 0; r < 4; r++)
      outB[(size_t)(r0 + r)*128 + col] = rrelu(acc2[jf][r] + bv);
  }
}

// ================= small kernels =================
__global__ void embed_k(const float* __restrict__ x,
                        const float* __restrict__ mean, const float* __restrict__ var,
                        const float* __restrict__ g, const float* __restrict__ b,
                        const float* __restrict__ Wn, const float* __restrict__ bnode,
                        float* __restrict__ nodeA,
                        const float* __restrict__ eattr,
                        const float* __restrict__ We, const float* __restrict__ be,
                        float* __restrict__ ea12,
                        const int* __restrict__ ei, const int* __restrict__ ei3,
                        float* __restrict__ cnt1, float* __restrict__ cnt2,
                        float* __restrict__ zptr) {
  int bid = blockIdx.x, t = threadIdx.x;
  if (bid < 2048) {
    int idx = bid * 256 + t;
    int n = idx >> 6, o = idx & 63;
    float acc = bnode[o];
    #pragma unroll
    for (int i = 0; i < 8; i++) {
      float xn = (x[n*8+i] - mean[i]) * rsqrtf(var[i] + BN_EPS) * g[i] + b[i];
      acc += xn * Wn[i*64 + o];
    }
    nodeA[idx] = rrelu(acc);
  } else if (bid < 2816) {
    int idx = (bid - 2048) * 256 + t;
    if (idx >= N_EDGES * 12) return;
    int e = idx / 12, j = idx - e * 12;
    float acc = be[j];
    #pragma unroll
    for (int k = 0; k < 19; k++) acc += eattr[e*19+k] * We[k*12 + j];
    ea12[idx] = rrelu(acc);
  } else if (bid < 2880) {
    int idx = (bid - 2816) * 256 + t;
    if (idx < N_EDGES) atomicAdd(&cnt1[ei[N_EDGES + idx]], 1.0f);
    if (idx < N_E3) {
      atomicAdd(&cnt2[ei3[N_E3 + idx]], 1.0f);
      atomicAdd(&cnt2[ei3[idx]], 1.0f);
    }
  } else {
    zero_tail(bid - 2880, zptr, N_NODES*64);
  }
}

// ======== pack v3: coalesced LDS tile transposes + elementwise copies + zero + x-stats ====
// blocks 0..191 elementwise; 192..223 W2fh tiles; 224..255 Wfold tiles;
// 256..267 Wz1h; 268..269 Wc1Th; 270..273 Wc2Th; 274..281 x-stats.
__global__ __launch_bounds__(256) void pack_k(const float* __restrict__ Wnn1,
                       const float* __restrict__ Wih1, const float* __restrict__ Whh1,
                       const float* __restrict__ Wc1,  const float* __restrict__ Wc2,
                       const float* __restrict__ Wnn2,
                       const float* __restrict__ Wih2, const float* __restrict__ Whh2,
                       const float* __restrict__ Ws_ih, const float* __restrict__ Ws_hh,
                       const float* __restrict__ x,
                       f16* __restrict__ Wz1h,
                       f16* __restrict__ Wih1h, f16* __restrict__ Whh1h,
                       f16* __restrict__ Wc1Th, f16* __restrict__ Wc2Th,
                       f16* __restrict__ W2fh,
                       f16* __restrict__ Wih2h, f16* __restrict__ Whh2h,
                       float* __restrict__ Wfold,
                       float* __restrict__ cnt1, float* __restrict__ cnt2,
                       float* __restrict__ bns1, float* __restrict__ bns2,
                       float* __restrict__ ysum, float* __restrict__ ysq,
                       float* __restrict__ mean, float* __restrict__ var) {
  __shared__ float tile[64][65];
  int bid = blockIdx.x, t = threadIdx.x;
  int col = t & 63, rq = t >> 6;

  if (bid < 192) {
    int idx = bid * 256 + t;
    if (idx < 49152) { Wih2h[idx] = (f16)Wih2[idx]; Whh2h[idx] = (f16)Whh2[idx]; }
    if (idx < 12288) { Wih1h[idx] = (f16)Wih1[idx]; Whh1h[idx] = (f16)Whh1[idx]; }
    if (idx < N_NODES) { cnt1[idx] = 0.f; cnt2[idx] = 0.f; }
    if (idx < 128) { bns1[idx] = 0.f; bns2[idx] = 0.f; }
    if (idx < 640) { ysum[idx] = 0.f; ysq[idx] = 0.f; }
    return;
  }
  if (bid >= 274) {  // x-stats: one block per feature
    int f = bid - 274;
    __shared__ float s1[256], s2[256];
    float a = 0.f, bq = 0.f;
    for (int n = t; n < N_NODES; n += 256) {
      float v = x[n*8 + f];
      a += v; bq += v*v;
    }
    s1[t] = a; s2[t] = bq; __syncthreads();
    for (int w = 128; w > 0; w >>= 1) {
      if (t < w) { s1[t] += s1[t+w]; s2[t] += s2[t+w]; }
      __syncthreads();
    }
    if (t == 0) {
      float m = s1[0] / (float)N_NODES;
      mean[f] = m;
      var[f]  = s2[0] / (float)N_NODES - m*m;
    }
    return;
  }

  // ---- tile transposes: load src[r][c] coalesced, write dst[c][r] coalesced ----
  const float *srcA = nullptr, *srcB = nullptr;
  int sAs = 0, sBs = 0, dsts = 0;
  f16* dstH = nullptr; float* dstF = nullptr;

  if (bid < 224) {            // W2fh: per kg [i][o] -> [o][i], 128x128, 4 tiles/kg
    int tt = bid - 192, kg = tt >> 2, ti = (tt >> 1) & 1, tj = tt & 1;
    srcA = Wnn2 + kg*16384 + (ti*64)*128 + tj*64;  sAs = 128;
    dstH = W2fh + kg*16384 + (tj*64)*128 + ti*64;  dsts = 128;
  } else if (bid < 256) {     // Wfold[i][j] = Ws_ih[j][i] (+Ws_hh[j][i] if i<128)
    int tt = bid - 224, bi = tt >> 3, bj = tt & 7;
    srcA = Ws_ih + (size_t)(bj*64)*256 + bi*64;  sAs = 256;
    if (bi*64 < 128) { srcB = Ws_hh + (size_t)(bj*64)*128 + bi*64; sBs = 128; }
    dstF = Wfold + (size_t)(bi*64)*512 + bj*64;  dsts = 512;
  } else if (bid < 268) {     // Wz1h: per kg [i][o] -> [o][i], 64x64
    int kg = bid - 256;
    srcA = Wnn1 + kg*4096;  sAs = 64;
    dstH = Wz1h + kg*4096;  dsts = 64;
  } else if (bid < 270) {     // Wc1Th [o][i] = Wc1[i][o], 64x128 -> 2 tiles
    int to = bid - 268;
    srcA = Wc1 + to*64;          sAs = 128;
    dstH = Wc1Th + (to*64)*64;   dsts = 64;
  } else {                    // Wc2Th [o][i] = Wc2[i][o], 128x128 -> 4 tiles
    int tt = bid - 270, ti = tt >> 1, to = tt & 1;
    srcA = Wc2 + (ti*64)*128 + to*64;          sAs = 128;
    dstH = Wc2Th + (to*64)*128 + ti*64;        dsts = 128;
  }

  #pragma unroll
  for (int p = 0; p < 16; p++) {
    int r = p*4 + rq;
    float v = srcA[(size_t)r*sAs + col];
    if (srcB) v += srcB[(size_t)r*sBs + col];
    tile[r][col] = v;
  }
  __syncthreads();
  if (dstH) {
    #pragma unroll
    for (int p = 0; p < 16; p++) {
      int c = p*4 + rq;
      dstH[(size_t)c*dsts + col] = (f16)tile[col][c];
    }
  } else {
    #pragma unroll
    for (int p = 0; p < 16; p++) {
      int c = p*4 + rq;
      dstF[(size_t)c*dsts + col] = tile[col][c];
    }
  }
}

// ---------- Set2Set ----------
__global__ __launch_bounds__(1024) void set2set_k(const float* __restrict__ x,
    const float* __restrict__ Wfold,
    const float* __restrict__ bs_ih, const float* __restrict__ bs_hh,
    float* __restrict__ qpool) {
  int g = blockIdx.x, t = threadIdx.x;
  __shared__ float xs[NPG*128];
  __shared__ float hr[256];
  __shared__ float cbuf[128];
  __shared__ float pbuf[1024];
  __shared__ float abuf[NPG];
  *(float4*)&xs[t*4] = *(const float4*)(x + (size_t)g*NPG*128 + t*4);
  if (t < 128) {
    float gi = bs_ih[t]     + bs_hh[t];
    float gg = bs_ih[256+t] + bs_hh[256+t];
    float go = bs_ih[384+t] + bs_hh[384+t];
    float c0 = sigm(gi) * tanhf(gg);
    cbuf[t] = c0;
    hr[t] = sigm(go) * tanhf(c0);
  }
  __syncthreads();
  #pragma unroll 1
  for (int step = 0; step < 3; step++) {
    {
      int node = t >> 5, s = t & 31;
      const float* xr = xs + node*128 + s*4;
      float pv = xr[0]*hr[s*4] + xr[1]*hr[s*4+1] + xr[2]*hr[s*4+2] + xr[3]*hr[s*4+3];
      pv += __shfl_down(pv, 16, 32); pv += __shfl_down(pv, 8, 32);
      pv += __shfl_down(pv, 4, 32);  pv += __shfl_down(pv, 2, 32);
      pv += __shfl_down(pv, 1, 32);
      if (s == 0) pbuf[node] = pv;
    }
    __syncthreads();
    if (t < NPG) {
      float e = pbuf[t];
      float mx = e;
      for (int o = 16; o > 0; o >>= 1) mx = fmaxf(mx, __shfl_xor(mx, o, 32));
      float ex = __expf(e - mx);
      float den = ex;
      for (int o = 16; o > 0; o >>= 1) den += __shfl_xor(den, o, 32);
      abuf[t] = ex / den;
    }
    __syncthreads();
    if (t < 128) {
      float r = 0.f;
      #pragma unroll 8
      for (int nn = 0; nn < NPG; nn++) r += abuf[nn] * xs[nn*128 + t];
      hr[128 + t] = r;
    }
    __syncthreads();
    if (step == 2) break;
    {
      int j = t & 511, half = t >> 9;
      const float* wp = Wfold + (size_t)(half*128)*512 + j;
      const float* iv = hr + half*128;
      float a0=0.f, a1=0.f, a2=0.f, a3=0.f;
      #pragma unroll 4
      for (int i = 0; i < 128; i += 4) {
        a0 += iv[i]   * wp[(i)  *512];
        a1 += iv[i+1] * wp[(i+1)*512];
        a2 += iv[i+2] * wp[(i+2)*512];
        a3 += iv[i+3] * wp[(i+3)*512];
      }
      pbuf[t] = a0 + a1 + a2 + a3;
    }
    __syncthreads();
    if (t < 128) {
      float gi = pbuf[t]     + pbuf[512+t] + bs_ih[t]     + bs_hh[t];
      float gf = pbuf[128+t] + pbuf[640+t] + bs_ih[128+t] + bs_hh[128+t];
      float gg = pbuf[256+t] + pbuf[768+t] + bs_ih[256+t] + bs_hh[256+t];
      float go = pbuf[384+t] + pbuf[896+t] + bs_ih[384+t] + bs_hh[384+t];
      float ci = sigm(gf) * cbuf[t] + sigm(gi) * tanhf(gg);
      cbuf[t] = ci;
      hr[t] = sigm(go) * tanhf(ci);
    }
    __syncthreads();
  }
  if (t < 256) qpool[g*256 + t] = hr[t];
}

// ======== yhat edge-major (coalesced) + column-sum atomics ========
__device__ __forceinline__ float yval(const float* __restrict__ feat,
                                      const float* __restrict__ qpool,
                                      int n0, int n1, int cb, int j) {
  if (j < 128)      return 0.5f*(feat[n0*128+j] + feat[n1*128+j]);
  else if (j < 256) { int jj=j-128; return feat[n0*128+jj]*feat[n1*128+jj]; }
  else if (j < 384) { int jj=j-256; float d=feat[n0*128+jj]-feat[n1*128+jj]; return d*d; }
  else              return qpool[cb*256 + (j-384)];
}

__global__ __launch_bounds__(256) void ys_k(const float* __restrict__ feat,
    const int* __restrict__ ei3, const int* __restrict__ batch,
    const float* __restrict__ qpool,
    float* __restrict__ yhat, float* __restrict__ ysum, float* __restrict__ ysq) {
  int t = threadIdx.x;
  int e0 = blockIdx.x * 8;   // 128 blocks
  float s0=0,q0=0,s1=0,q1=0,s2=0,q2=0;
  for (int ee = 0; ee < 8; ee++) {
    int e = e0 + ee;
    int n0 = ei3[e], n1 = ei3[N_E3 + e];
    int cb = batch[n0];
    float v0 = yval(feat, qpool, n0, n1, cb, t);
    yhat[(size_t)e*640 + t] = v0; s0 += v0; q0 += v0*v0;
    float v1 = yval(feat, qpool, n0, n1, cb, t + 256);
    yhat[(size_t)e*640 + t + 256] = v1; s1 += v1; q1 += v1*v1;
    if (t < 128) {
      float v2 = yval(feat, qpool, n0, n1, cb, t + 512);
      yhat[(size_t)e*640 + t + 512] = v2; s2 += v2; q2 += v2*v2;
    }
  }
  atomicAdd(&ysum[t], s0);        atomicAdd(&ysq[t], q0);
  atomicAdd(&ysum[t + 256], s1);  atomicAdd(&ysq[t + 256], q1);
  if (t < 128) { atomicAdd(&ysum[t + 512], s2); atomicAdd(&ysq[t + 512], q2); }
}

__global__ void final_k(const float* __restrict__ yhat,
                        const float* __restrict__ ysum, const float* __restrict__ ysq,
                        const float* __restrict__ g, const float* __restrict__ b,
                        const float* __restrict__ ea3,
                        const float* __restrict__ Ww, const float* __restrict__ Wb,
                        float* __restrict__ out) {
  int e = blockIdx.x, t = threadIdx.x;
  __shared__ float red[128];
  const float invE = 1.f / (float)N_E3;
  float av[8];
  #pragma unroll
  for (int k = 0; k < 8; k++) av[k] = ea3[e*8 + k];
  float acc = 0.f;
  for (int j = t; j < 640; j += 128) {
    float m = ysum[j] * invE;
    float v = ysq[j] * invE - m*m;
    float yn = (yhat[(size_t)e*640 + j] - m) * rsqrtf(v + BN_EPS) * g[j] + b[j];
    float wj = 0.f;
    #pragma unroll
    for (int k = 0; k < 8; k++) wj += av[k] * Ww[k*640 + j];
    acc += yn * wj;
  }
  red[t] = acc; __syncthreads();
  for (int w = 64; w > 0; w >>= 1) {
    if (t < w) red[t] += red[t+w];
    __syncthreads();
  }
  if (t == 0) {
    float bb = 0.f;
    #pragma unroll
    for (int k = 0; k < 8; k++) bb += av[k] * Wb[k];
    out[e] = red[0] + bb;
  }
}

extern "C" void kernel_launch(void* const* d_in, const int* in_sizes, int n_in,
                              void* d_out, int out_size, void* d_ws, size_t ws_size,
                              hipStream_t stream) {
  const float* x      = (const float*)d_in[0];
  const int*   ei     = (const int*)  d_in[1];
  const float* eattr  = (const float*)d_in[2];
  const int*   ei3    = (const int*)  d_in[3];
  const float* ea3    = (const float*)d_in[4];
  const int*   batch  = (const int*)  d_in[5];
  const float* bnx_g  = (const float*)d_in[6];
  const float* bnx_b  = (const float*)d_in[7];
  const float* Wn     = (const float*)d_in[8];
  const float* bnode  = (const float*)d_in[9];
  const float* We     = (const float*)d_in[10];
  const float* be     = (const float*)d_in[11];
  const float* Wnn1   = (const float*)d_in[12];
  const float* bias1  = (const float*)d_in[13];
  const float* Wih1   = (const float*)d_in[14];
  const float* Whh1   = (const float*)d_in[15];
  const float* bih1   = (const float*)d_in[16];
  const float* bhh1   = (const float*)d_in[17];
  const float* bnc_g  = (const float*)d_in[18];
  const float* bnc_b  = (const float*)d_in[19];
  const float* Wc1    = (const float*)d_in[20];
  const float* bc1    = (const float*)d_in[21];
  const float* Wc2    = (const float*)d_in[22];
  const float* bc2    = (const float*)d_in[23];
  const float* Wnn2   = (const float*)d_in[24];
  const float* bias2  = (const float*)d_in[25];
  const float* Wih2   = (const float*)d_in[26];
  const float* Whh2   = (const float*)d_in[27];
  const float* bih2   = (const float*)d_in[28];
  const float* bhh2   = (const float*)d_in[29];
  const float* Ws_ih  = (const float*)d_in[30];
  const float* Ws_hh  = (const float*)d_in[31];
  const float* bs_ih  = (const float*)d_in[32];
  const float* bs_hh  = (const float*)d_in[33];
  const float* bno_g  = (const float*)d_in[34];
  const float* bno_b  = (const float*)d_in[35];
  const float* Ww     = (const float*)d_in[36];
  const float* Wb     = (const float*)d_in[37];
  float* out = (float*)d_out;

  // workspace carve-up
  float* W = (float*)d_ws;
  size_t off = 0;
  float* Wfold  = W + off; off += 131072;
  float* ea12   = W + off; off += (size_t)N_EDGES * 12;
  float* nodeA  = W + off; off += (size_t)N_NODES * 64;
  float* nodeA2 = W + off; off += (size_t)N_NODES * 64;
  float* sA1    = W + off; off += (size_t)N_NODES * 64;
  float* sA2    = W + off; off += (size_t)N_NODES * 64;
  float* sB1    = W + off; off += (size_t)N_NODES * 128;
  float* sB2    = W + off; off += (size_t)N_NODES * 128;
  float* cnt1   = W + off; off += (size_t)N_NODES;
  float* cnt2   = W + off; off += (size_t)N_NODES;
  float* nodeB  = W + off; off += (size_t)N_NODES * 128;
  float* nodeB2 = W + off; off += (size_t)N_NODES * 128;
  float* qpool  = W + off; off += (size_t)NGRAPH * 256;
  float* yhat   = W + off; off += (size_t)N_E3 * 640;
  float* mean   = W + off; off += 640;
  float* var    = W + off; off += 640;
  float* bns1   = W + off; off += 128;
  float* bns2   = W + off; off += 128;
  float* ysum   = W + off; off += 640;
  float* ysq    = W + off; off += 640;
  f16* F = (f16*)(W + off);
  size_t foff = 0;
  f16* Wz1h  = F + foff; foff += 49152;
  f16* Wih1h = F + foff; foff += 12288;
  f16* Whh1h = F + foff; foff += 12288;
  f16* Wc1Th = F + foff; foff += 8192;
  f16* Wc2Th = F + foff; foff += 16384;
  f16* W2fh  = F + foff; foff += 131072;
  f16* Wih2h = F + foff; foff += 49152;
  f16* Whh2h = F + foff; foff += 49152;
  (void)foff; (void)ws_size; (void)in_sizes; (void)n_in; (void)out_size;

  // 1. pack v3 (tiles + copies + zero + x-stats)
  pack_k<<<282, 256, 0, stream>>>(Wnn1, Wih1, Whh1, Wc1, Wc2, Wnn2, Wih2, Whh2, Ws_ih, Ws_hh, x,
                                  Wz1h, Wih1h, Whh1h, Wc1Th, Wc2Th, W2fh, Wih2h, Whh2h,
                                  Wfold, cnt1, cnt2, bns1, bns2, ysum, ysq, mean, var);
  // 2. embeds (+cnt atomics, +zero sA1)
  embed_k<<<2896, 256, 0, stream>>>(x, mean, var, bnx_g, bnx_b, Wn, bnode, nodeA,
                                    eattr, We, be, ea12, ei, ei3, cnt1, cnt2, sA1);

  // 3-6. layer-1 x2 (ping-pong h and sbuf)
  conv1f_k<<<256, 256, 0, stream>>>(nodeA, ei, ea12, Wz1h, sA1);
  gruf_k<6,0><<<272, 128, 0, stream>>>(sA1, cnt1, bias1, Wih1h, Whh1h, bih1, bhh1,
                                       nodeA, nodeA2, nullptr, nullptr,
                                       256, sA2, N_NODES*64);
  conv1f_k<<<256, 256, 0, stream>>>(nodeA2, ei, ea12, Wz1h, sA2);
  gruf_k<6,1><<<272, 128, 0, stream>>>(sA2, cnt1, bias1, Wih1h, Whh1h, bih1, bhh1,
                                       nodeA2, nodeA, bns1, bns2,
                                       256, sB1, N_NODES*128);

  // 7. fused BN + FC1 + FC2 (+zero sB2)
  fcf_k<<<144, 256, 0, stream>>>(nodeA, Wc1Th, bc1, Wc2Th, bc2,
                                 bns1, bns2, bnc_g, bnc_b, nodeB,
                                 128, sB2, N_NODES*128);

  // 8-11. layer-2 x2
  conv2f_k<<<256, 512, 0, stream>>>(nodeB, ei3, ea3, W2fh, sB1);
  gruf_k<7,0><<<256, 256, 0, stream>>>(sB1, cnt2, bias2, Wih2h, Whh2h, bih2, bhh2,
                                       nodeB, nodeB2, nullptr, nullptr,
                                       256, nullptr, 0);
  conv2f_k<<<256, 512, 0, stream>>>(nodeB2, ei3, ea3, W2fh, sB2);
  gruf_k<7,0><<<256, 256, 0, stream>>>(sB2, cnt2, bias2, Wih2h, Whh2h, bih2, bhh2,
                                       nodeB2, nodeB, nullptr, nullptr,
                                       256, nullptr, 0);

  // 12. set2set
  set2set_k<<<NGRAPH, 1024, 0, stream>>>(nodeB, Wfold, bs_ih, bs_hh, qpool);

  // 13. yhat (coalesced) + column sums
  ys_k<<<128, 256, 0, stream>>>(nodeB, ei3, batch, qpool, yhat, ysum, ysq);

  // 14. weighted sum (BN from sums)
  final_k<<<N_E3, 128, 0, stream>>>(yhat, ysum, ysq, bno_g, bno_b, ea3, Ww, Wb, out);
}

// Round 14
// 191.204 us; speedup vs baseline: 2.8179x; 1.0284x over previous
//
#include <hip/hip_runtime.h>
#include <hip/hip_bf16.h>
#include <math.h>

#define N_NODES 8192
#define N_EDGES 16384
#define N_E3    1024
#define NGRAPH  256
#define NPG     32
#define SLOPE   (11.0f/48.0f)
#define BN_EPS  1e-5f

__device__ __forceinline__ float rrelu(float v){ return v >= 0.f ? v : SLOPE*v; }
__device__ __forceinline__ float sigm(float v){ return 1.f/(1.f+__expf(-v)); }

typedef _Float16 f16;
typedef __attribute__((ext_vector_type(8))) _Float16 half8v;
typedef __attribute__((ext_vector_type(4))) float f32x4;

__device__ __forceinline__ void zero_tail(int zb, float* zptr, int zcount) {
  float4 z4 = make_float4(0.f,0.f,0.f,0.f);
  int bd = blockDim.x;
  for (int i = zb*bd + (int)threadIdx.x; i*4 < zcount; i += 16*bd)
    ((float4*)zptr)[i] = z4;
}

// ======== conv1 fused, kg-split x2: 512 blocks x 256 thr (eg = blk>>1, kgh = blk&1) ====
__global__ __launch_bounds__(256) void conv1f_k(const float* __restrict__ nodeA,
    const int* __restrict__ ei, const float* __restrict__ ea,
    const f16* __restrict__ Wz1h, float* __restrict__ sbuf) {
  int t = threadIdx.x, lane = t & 63, wv = t >> 6;
  int eg = blockIdx.x >> 1, kgh = blockIdx.x & 1;
  int e0 = eg*64 + wv*16;
  int eA = e0 + (lane & 15);
  int src = ei[eA];
  int kb0 = (lane >> 4) * 8;
  const float* ap = nodeA + (size_t)src*64 + kb0;
  float4 v0 = *(const float4*)ap,      v1 = *(const float4*)(ap+4);
  float4 v2 = *(const float4*)(ap+32), v3 = *(const float4*)(ap+36);
  half8v a0, a1;
  a0[0]=(f16)v0.x; a0[1]=(f16)v0.y; a0[2]=(f16)v0.z; a0[3]=(f16)v0.w;
  a0[4]=(f16)v1.x; a0[5]=(f16)v1.y; a0[6]=(f16)v1.z; a0[7]=(f16)v1.w;
  a1[0]=(f16)v2.x; a1[1]=(f16)v2.y; a1[2]=(f16)v2.z; a1[3]=(f16)v2.w;
  a1[4]=(f16)v3.x; a1[5]=(f16)v3.y; a1[6]=(f16)v3.z; a1[7]=(f16)v3.w;
  float eav[6];
  #pragma unroll
  for (int kk = 0; kk < 6; kk++) eav[kk] = ea[eA*12 + kgh*6 + kk];

  f32x4 acc[4] = {{0,0,0,0},{0,0,0,0},{0,0,0,0},{0,0,0,0}};
  #pragma unroll
  for (int kk = 0; kk < 6; kk++) {
    int kg = kgh*6 + kk;
    f16 s = (f16)eav[kk];
    half8v s0, s1;
    #pragma unroll
    for (int u = 0; u < 8; u++) { s0[u] = a0[u]*s; s1[u] = a1[u]*s; }
    #pragma unroll
    for (int jf = 0; jf < 4; jf++) {
      const f16* wp = Wz1h + (size_t)(kg*64 + jf*16 + (lane & 15))*64 + kb0;
      acc[jf] = __builtin_amdgcn_mfma_f32_16x16x32_f16(s0, *(const half8v*)wp, acc[jf], 0, 0, 0);
      acc[jf] = __builtin_amdgcn_mfma_f32_16x16x32_f16(s1, *(const half8v*)(wp+32), acc[jf], 0, 0, 0);
    }
  }
  int dstv[4];
  #pragma unroll
  for (int r = 0; r < 4; r++) dstv[r] = ei[N_EDGES + e0 + ((lane>>4)<<2) + r];
  #pragma unroll
  for (int jf = 0; jf < 4; jf++) {
    int col = jf*16 + (lane & 15);
    #pragma unroll
    for (int r = 0; r < 4; r++)
      atomicAdd(&sbuf[dstv[r]*64 + col], acc[jf][r]);
  }
}

// ======== conv2 fused: 256 blocks x 512 thr (unchanged) ========
__global__ __launch_bounds__(512) void conv2f_k(const float* __restrict__ nodeB,
    const int* __restrict__ ei3, const float* __restrict__ ea3,
    const f16* __restrict__ W2fh, float* __restrict__ sbuf) {
  int t = threadIdx.x, lane = t & 63, wv = t >> 6;
  int eg = blockIdx.x >> 1, qh = blockIdx.x & 1;
  int kgh = wv >> 2, jp = wv & 3;
  int e0 = eg * 16;
  int eA = e0 + (lane & 15);
  int src = ei3[eA];
  int kb0 = qh*64 + (lane >> 4) * 8;
  const float* ap = nodeB + (size_t)src*128 + kb0;
  half8v a0, a1;
  {
    float4 w0 = *(const float4*)ap,        w1 = *(const float4*)(ap+4);
    float4 w2 = *(const float4*)(ap + 32), w3 = *(const float4*)(ap+36);
    a0[0]=(f16)w0.x; a0[1]=(f16)w0.y; a0[2]=(f16)w0.z; a0[3]=(f16)w0.w;
    a0[4]=(f16)w1.x; a0[5]=(f16)w1.y; a0[6]=(f16)w1.z; a0[7]=(f16)w1.w;
    a1[0]=(f16)w2.x; a1[1]=(f16)w2.y; a1[2]=(f16)w2.z; a1[3]=(f16)w2.w;
    a1[4]=(f16)w3.x; a1[5]=(f16)w3.y; a1[6]=(f16)w3.z; a1[7]=(f16)w3.w;
  }
  int eb = eA & (N_E3 - 1);
  float eav[4];
  #pragma unroll
  for (int kk = 0; kk < 4; kk++) eav[kk] = ea3[eb*8 + kgh*4 + kk];

  f32x4 acc[2] = {{0,0,0,0},{0,0,0,0}};
  #pragma unroll
  for (int kk = 0; kk < 4; kk++) {
    f16 s = (f16)eav[kk];
    half8v s0, s1;
    #pragma unroll
    for (int u = 0; u < 8; u++) { s0[u] = a0[u]*s; s1[u] = a1[u]*s; }
    int kg = kgh*4 + kk;
    #pragma unroll
    for (int jj = 0; jj < 2; jj++) {
      int jf = jp*2 + jj;
      const f16* wp = W2fh + (size_t)(kg*128 + jf*16 + (lane & 15))*128 + kb0;
      acc[jj] = __builtin_amdgcn_mfma_f32_16x16x32_f16(s0, *(const half8v*)wp, acc[jj], 0, 0, 0);
      acc[jj] = __builtin_amdgcn_mfma_f32_16x16x32_f16(s1, *(const half8v*)(wp+32), acc[jj], 0, 0, 0);
    }
  }
  int dstv[4];
  #pragma unroll
  for (int r = 0; r < 4; r++) dstv[r] = ei3[(e0 + ((lane>>4)<<2) + r + N_E3) & (2*N_E3 - 1)];
  #pragma unroll
  for (int jj = 0; jj < 2; jj++) {
    int col = (jp*2+jj)*16 + (lane & 15);
    #pragma unroll
    for (int r = 0; r < 4; r++)
      atomicAdd(&sbuf[dstv[r]*128 + col], acc[jj][r]);
  }
}

// ======== fused GRU, col-split: wave owns 16 rows x 16*JW cols; ncolg = H/(16*JW) = 4 ====
template<int LOGH, int STATS, int JW>
__global__ __launch_bounds__(256) void gruf_k(const float* __restrict__ sbuf,
                       const float* __restrict__ cnt,
                       const float* __restrict__ mbias,
                       const f16* __restrict__ Wih, const f16* __restrict__ Whh,
                       const float* __restrict__ bih, const float* __restrict__ bhh,
                       const float* __restrict__ hold, float* __restrict__ hnew,
                       float* __restrict__ bns1, float* __restrict__ bns2,
                       int nblk, float* __restrict__ zptr, int zcount) {
  if ((int)blockIdx.x >= nblk) { zero_tail(blockIdx.x - nblk, zptr, zcount); return; }
  const int H = 1 << LOGH;
  const int K = H;
  int t = threadIdx.x;
  int lane = t & 63, wv = t >> 6;
  int task = blockIdx.x * 4 + wv;
  int rowg = task >> 2, colg = task & 3;
  int n0 = rowg << 4;
  int j0 = colg * 16 * JW;
  int row = n0 + (lane & 15);
  int kb0 = (lane >> 4) * 8;

  f32x4 aR[JW], aZ[JW], aIN[JW], aHN[JW];
  #pragma unroll
  for (int j = 0; j < JW; j++) {
    aR[j] = (f32x4){0,0,0,0}; aZ[j] = (f32x4){0,0,0,0};
    aIN[j] = (f32x4){0,0,0,0}; aHN[j] = (f32x4){0,0,0,0};
  }

  float dn = 1.f / fmaxf(cnt[row], 1.0f);
  for (int k0 = 0; k0 < K; k0 += 32) {
    int kb = k0 + kb0;
    const float* ap = sbuf + (size_t)row * K + kb;
    float4 v0 = *(const float4*)ap, v1 = *(const float4*)(ap + 4);
    float4 b0 = *(const float4*)(mbias + kb), b1 = *(const float4*)(mbias + kb + 4);
    half8v af;
    af[0]=(f16)rrelu(v0.x*dn+b0.x); af[1]=(f16)rrelu(v0.y*dn+b0.y);
    af[2]=(f16)rrelu(v0.z*dn+b0.z); af[3]=(f16)rrelu(v0.w*dn+b0.w);
    af[4]=(f16)rrelu(v1.x*dn+b1.x); af[5]=(f16)rrelu(v1.y*dn+b1.y);
    af[6]=(f16)rrelu(v1.z*dn+b1.z); af[7]=(f16)rrelu(v1.w*dn+b1.w);
    #pragma unroll
    for (int jf = 0; jf < JW; jf++) {
      int wr = j0 + jf*16 + (lane & 15);
      half8v wR = *(const half8v*)(Wih + (size_t)wr*K + kb);
      half8v wZ = *(const half8v*)(Wih + (size_t)(H + wr)*K + kb);
      half8v wN = *(const half8v*)(Wih + (size_t)(2*H + wr)*K + kb);
      aR[jf]  = __builtin_amdgcn_mfma_f32_16x16x32_f16(af, wR, aR[jf], 0, 0, 0);
      aZ[jf]  = __builtin_amdgcn_mfma_f32_16x16x32_f16(af, wZ, aZ[jf], 0, 0, 0);
      aIN[jf] = __builtin_amdgcn_mfma_f32_16x16x32_f16(af, wN, aIN[jf], 0, 0, 0);
    }
  }
  for (int k0 = 0; k0 < K; k0 += 32) {
    int kb = k0 + kb0;
    const float* ap = hold + (size_t)row * K + kb;
    float4 v0 = *(const float4*)ap, v1 = *(const float4*)(ap + 4);
    half8v af;
    af[0]=(f16)v0.x; af[1]=(f16)v0.y; af[2]=(f16)v0.z; af[3]=(f16)v0.w;
    af[4]=(f16)v1.x; af[5]=(f16)v1.y; af[6]=(f16)v1.z; af[7]=(f16)v1.w;
    #pragma unroll
    for (int jf = 0; jf < JW; jf++) {
      int wr = j0 + jf*16 + (lane & 15);
      half8v wR = *(const half8v*)(Whh + (size_t)wr*K + kb);
      half8v wZ = *(const half8v*)(Whh + (size_t)(H + wr)*K + kb);
      half8v wN = *(const half8v*)(Whh + (size_t)(2*H + wr)*K + kb);
      aR[jf]  = __builtin_amdgcn_mfma_f32_16x16x32_f16(af, wR, aR[jf], 0, 0, 0);
      aZ[jf]  = __builtin_amdgcn_mfma_f32_16x16x32_f16(af, wZ, aZ[jf], 0, 0, 0);
      aHN[jf] = __builtin_amdgcn_mfma_f32_16x16x32_f16(af, wN, aHN[jf], 0, 0, 0);
    }
  }
  int r0 = n0 + ((lane >> 4) << 2);
  #pragma unroll
  for (int jf = 0; jf < JW; jf++) {
    int col = j0 + jf*16 + (lane & 15);
    float bR = bih[col] + bhh[col];
    float bZ = bih[H + col] + bhh[H + col];
    float bI = bih[2*H + col], bH = bhh[2*H + col];
    float ssum = 0.f, sq = 0.f;
    #pragma unroll
    for (int r = 0; r < 4; r++) {
      float rr = sigm(aR[jf][r] + bR);
      float zz = sigm(aZ[jf][r] + bZ);
      float nn = tanhf(aIN[jf][r] + bI + rr*(aHN[jf][r] + bH));
      float ho = hold[(size_t)(r0 + r)*H + col];
      float hv = (1.f - zz)*nn + zz*ho;
      hnew[(size_t)(r0 + r)*H + col] = hv;
      if (STATS) { ssum += hv; sq += hv*hv; }
    }
    if (STATS) {
      ssum += __shfl_xor(ssum, 16); ssum += __shfl_xor(ssum, 32);
      sq   += __shfl_xor(sq, 16);   sq   += __shfl_xor(sq, 32);
      if (lane < 16) { atomicAdd(&bns1[col], ssum); atomicAdd(&bns2[col], sq); }
    }
  }
}

// ======== fused FC1+FC2: 2-wave blocks, 16 rows; waves split jf halves ========
__global__ __launch_bounds__(128) void fcf_k(const float* __restrict__ A,
    const f16* __restrict__ W1, const float* __restrict__ b1v,
    const f16* __restrict__ W2, const float* __restrict__ b2v,
    const float* __restrict__ bns1, const float* __restrict__ bns2,
    const float* __restrict__ g, const float* __restrict__ b,
    float* __restrict__ outB,
    int nblk, float* __restrict__ zptr, int zcount) {
  if ((int)blockIdx.x >= nblk) { zero_tail(blockIdx.x - nblk, zptr, zcount); return; }
  __shared__ f16 y1s[16][128];
  int t = threadIdx.x, lane = t & 63, wv = t >> 6;   // 2 waves
  int n0 = blockIdx.x * 16;
  int row = n0 + (lane & 15);
  int kb0 = (lane >> 4) * 8;
  const float invN = 1.f / (float)N_NODES;

  const float* ap = A + (size_t)row*64 + kb0;
  half8v af0, af1;
  #pragma unroll
  for (int u = 0; u < 8; u++) {
    int k0i = kb0 + u, k1i = 32 + kb0 + u;
    float m0 = bns1[k0i]*invN, m1 = bns1[k1i]*invN;
    float va0 = bns2[k0i]*invN - m0*m0, va1 = bns2[k1i]*invN - m1*m1;
    af0[u] = (f16)((ap[u]    - m0)*rsqrtf(va0+BN_EPS)*g[k0i] + b[k0i]);
    af1[u] = (f16)((ap[32+u] - m1)*rsqrtf(va1+BN_EPS)*g[k1i] + b[k1i]);
  }
  f32x4 acc1[4] = {{0,0,0,0},{0,0,0,0},{0,0,0,0},{0,0,0,0}};
  #pragma unroll
  for (int jj = 0; jj < 4; jj++) {
    int jf = wv*4 + jj;
    const f16* wp = W1 + (size_t)(jf*16 + (lane & 15))*64 + kb0;
    acc1[jj] = __builtin_amdgcn_mfma_f32_16x16x32_f16(af0, *(const half8v*)wp, acc1[jj], 0, 0, 0);
    acc1[jj] = __builtin_amdgcn_mfma_f32_16x16x32_f16(af1, *(const half8v*)(wp+32), acc1[jj], 0, 0, 0);
  }
  #pragma unroll
  for (int jj = 0; jj < 4; jj++) {
    int col = (wv*4+jj)*16 + (lane & 15);
    float bv = b1v[col];
    #pragma unroll
    for (int r = 0; r < 4; r++) {
      int rl = ((lane >> 4) << 2) + r;
      y1s[rl][col] = (f16)rrelu(acc1[jj][r] + bv);
    }
  }
  __syncthreads();
  half8v bf[4];
  #pragma unroll
  for (int q = 0; q < 4; q++)
    bf[q] = *(const half8v*)&y1s[lane & 15][q*32 + kb0];
  f32x4 acc2[4] = {{0,0,0,0},{0,0,0,0},{0,0,0,0},{0,0,0,0}};
  #pragma unroll
  for (int jj = 0; jj < 4; jj++) {
    int jf = wv*4 + jj;
    const f16* wp = W2 + (size_t)(jf*16 + (lane & 15))*128 + kb0;
    #pragma unroll
    for (int q = 0; q < 4; q++)
      acc2[jj] = __builtin_amdgcn_mfma_f32_16x16x32_f16(bf[q], *(const half8v*)(wp + q*32), acc2[jj], 0, 0, 0);
  }
  int r0 = n0 + ((lane >> 4) << 2);
  #pragma unroll
  for (int jj = 0; jj < 4; jj++) {
    int col = (wv*4+jj)*16 + (lane & 15);
    float bv = b2v[col];
    #pragma unroll
    for (int r = 0; r < 4; r++)
      outB[(size_t)(r0 + r)*128 + col] = rrelu(acc2[jj][r] + bv);
  }
}

// ================= small kernels =================
__global__ void embed_k(const float* __restrict__ x,
                        const float* __restrict__ mean, const float* __restrict__ var,
                        const float* __restrict__ g, const float* __restrict__ b,
                        const float* __restrict__ Wn, const float* __restrict__ bnode,
                        float* __restrict__ nodeA,
                        const float* __restrict__ eattr,
                        const float* __restrict__ We, const float* __restrict__ be,
                        float* __restrict__ ea12,
                        const int* __restrict__ ei, const int* __restrict__ ei3,
                        float* __restrict__ cnt1, float* __restrict__ cnt2,
                        float* __restrict__ zptr) {
  int bid = blockIdx.x, t = threadIdx.x;
  if (bid < 2048) {
    int idx = bid * 256 + t;
    int n = idx >> 6, o = idx & 63;
    float acc = bnode[o];
    #pragma unroll
    for (int i = 0; i < 8; i++) {
      float xn = (x[n*8+i] - mean[i]) * rsqrtf(var[i] + BN_EPS) * g[i] + b[i];
      acc += xn * Wn[i*64 + o];
    }
    nodeA[idx] = rrelu(acc);
  } else if (bid < 2816) {
    int idx = (bid - 2048) * 256 + t;
    if (idx >= N_EDGES * 12) return;
    int e = idx / 12, j = idx - e * 12;
    float acc = be[j];
    #pragma unroll
    for (int k = 0; k < 19; k++) acc += eattr[e*19+k] * We[k*12 + j];
    ea12[idx] = rrelu(acc);
  } else if (bid < 2880) {
    int idx = (bid - 2816) * 256 + t;
    if (idx < N_EDGES) atomicAdd(&cnt1[ei[N_EDGES + idx]], 1.0f);
    if (idx < N_E3) {
      atomicAdd(&cnt2[ei3[N_E3 + idx]], 1.0f);
      atomicAdd(&cnt2[ei3[idx]], 1.0f);
    }
  } else {
    zero_tail(bid - 2880, zptr, N_NODES*64);
  }
}

// ======== pack v3 (unchanged from R13) ========
__global__ __launch_bounds__(256) void pack_k(const float* __restrict__ Wnn1,
                       const float* __restrict__ Wih1, const float* __restrict__ Whh1,
                       const float* __restrict__ Wc1,  const float* __restrict__ Wc2,
                       const float* __restrict__ Wnn2,
                       const float* __restrict__ Wih2, const float* __restrict__ Whh2,
                       const float* __restrict__ Ws_ih, const float* __restrict__ Ws_hh,
                       const float* __restrict__ x,
                       f16* __restrict__ Wz1h,
                       f16* __restrict__ Wih1h, f16* __restrict__ Whh1h,
                       f16* __restrict__ Wc1Th, f16* __restrict__ Wc2Th,
                       f16* __restrict__ W2fh,
                       f16* __restrict__ Wih2h, f16* __restrict__ Whh2h,
                       float* __restrict__ Wfold,
                       float* __restrict__ cnt1, float* __restrict__ cnt2,
                       float* __restrict__ bns1, float* __restrict__ bns2,
                       float* __restrict__ ysum, float* __restrict__ ysq,
                       float* __restrict__ mean, float* __restrict__ var) {
  __shared__ float tile[64][65];
  int bid = blockIdx.x, t = threadIdx.x;
  int col = t & 63, rq = t >> 6;

  if (bid < 192) {
    int idx = bid * 256 + t;
    if (idx < 49152) { Wih2h[idx] = (f16)Wih2[idx]; Whh2h[idx] = (f16)Whh2[idx]; }
    if (idx < 12288) { Wih1h[idx] = (f16)Wih1[idx]; Whh1h[idx] = (f16)Whh1[idx]; }
    if (idx < N_NODES) { cnt1[idx] = 0.f; cnt2[idx] = 0.f; }
    if (idx < 128) { bns1[idx] = 0.f; bns2[idx] = 0.f; }
    if (idx < 640) { ysum[idx] = 0.f; ysq[idx] = 0.f; }
    return;
  }
  if (bid >= 274) {
    int f = bid - 274;
    __shared__ float s1[256], s2[256];
    float a = 0.f, bq = 0.f;
    for (int n = t; n < N_NODES; n += 256) {
      float v = x[n*8 + f];
      a += v; bq += v*v;
    }
    s1[t] = a; s2[t] = bq; __syncthreads();
    for (int w = 128; w > 0; w >>= 1) {
      if (t < w) { s1[t] += s1[t+w]; s2[t] += s2[t+w]; }
      __syncthreads();
    }
    if (t == 0) {
      float m = s1[0] / (float)N_NODES;
      mean[f] = m;
      var[f]  = s2[0] / (float)N_NODES - m*m;
    }
    return;
  }

  const float *srcA = nullptr, *srcB = nullptr;
  int sAs = 0, sBs = 0, dsts = 0;
  f16* dstH = nullptr; float* dstF = nullptr;

  if (bid < 224) {
    int tt = bid - 192, kg = tt >> 2, ti = (tt >> 1) & 1, tj = tt & 1;
    srcA = Wnn2 + kg*16384 + (ti*64)*128 + tj*64;  sAs = 128;
    dstH = W2fh + kg*16384 + (tj*64)*128 + ti*64;  dsts = 128;
  } else if (bid < 256) {
    int tt = bid - 224, bi = tt >> 3, bj = tt & 7;
    srcA = Ws_ih + (size_t)(bj*64)*256 + bi*64;  sAs = 256;
    if (bi*64 < 128) { srcB = Ws_hh + (size_t)(bj*64)*128 + bi*64; sBs = 128; }
    dstF = Wfold + (size_t)(bi*64)*512 + bj*64;  dsts = 512;
  } else if (bid < 268) {
    int kg = bid - 256;
    srcA = Wnn1 + kg*4096;  sAs = 64;
    dstH = Wz1h + kg*4096;  dsts = 64;
  } else if (bid < 270) {
    int to = bid - 268;
    srcA = Wc1 + to*64;          sAs = 128;
    dstH = Wc1Th + (to*64)*64;   dsts = 64;
  } else {
    int tt = bid - 270, ti = tt >> 1, to = tt & 1;
    srcA = Wc2 + (ti*64)*128 + to*64;          sAs = 128;
    dstH = Wc2Th + (to*64)*128 + ti*64;        dsts = 128;
  }

  #pragma unroll
  for (int p = 0; p < 16; p++) {
    int r = p*4 + rq;
    float v = srcA[(size_t)r*sAs + col];
    if (srcB) v += srcB[(size_t)r*sBs + col];
    tile[r][col] = v;
  }
  __syncthreads();
  if (dstH) {
    #pragma unroll
    for (int p = 0; p < 16; p++) {
      int c = p*4 + rq;
      dstH[(size_t)c*dsts + col] = (f16)tile[col][c];
    }
  } else {
    #pragma unroll
    for (int p = 0; p < 16; p++) {
      int c = p*4 + rq;
      dstF[(size_t)c*dsts + col] = tile[col][c];
    }
  }
}

// ---------- Set2Set ----------
__global__ __launch_bounds__(1024) void set2set_k(const float* __restrict__ x,
    const float* __restrict__ Wfold,
    const float* __restrict__ bs_ih, const float* __restrict__ bs_hh,
    float* __restrict__ qpool) {
  int g = blockIdx.x, t = threadIdx.x;
  __shared__ float xs[NPG*128];
  __shared__ float hr[256];
  __shared__ float cbuf[128];
  __shared__ float pbuf[1024];
  __shared__ float abuf[NPG];
  *(float4*)&xs[t*4] = *(const float4*)(x + (size_t)g*NPG*128 + t*4);
  if (t < 128) {
    float gi = bs_ih[t]     + bs_hh[t];
    float gg = bs_ih[256+t] + bs_hh[256+t];
    float go = bs_ih[384+t] + bs_hh[384+t];
    float c0 = sigm(gi) * tanhf(gg);
    cbuf[t] = c0;
    hr[t] = sigm(go) * tanhf(c0);
  }
  __syncthreads();
  #pragma unroll 1
  for (int step = 0; step < 3; step++) {
    {
      int node = t >> 5, s = t & 31;
      const float* xr = xs + node*128 + s*4;
      float pv = xr[0]*hr[s*4] + xr[1]*hr[s*4+1] + xr[2]*hr[s*4+2] + xr[3]*hr[s*4+3];
      pv += __shfl_down(pv, 16, 32); pv += __shfl_down(pv, 8, 32);
      pv += __shfl_down(pv, 4, 32);  pv += __shfl_down(pv, 2, 32);
      pv += __shfl_down(pv, 1, 32);
      if (s == 0) pbuf[node] = pv;
    }
    __syncthreads();
    if (t < NPG) {
      float e = pbuf[t];
      float mx = e;
      for (int o = 16; o > 0; o >>= 1) mx = fmaxf(mx, __shfl_xor(mx, o, 32));
      float ex = __expf(e - mx);
      float den = ex;
      for (int o = 16; o > 0; o >>= 1) den += __shfl_xor(den, o, 32);
      abuf[t] = ex / den;
    }
    __syncthreads();
    if (t < 128) {
      float r = 0.f;
      #pragma unroll 8
      for (int nn = 0; nn < NPG; nn++) r += abuf[nn] * xs[nn*128 + t];
      hr[128 + t] = r;
    }
    __syncthreads();
    if (step == 2) break;
    {
      int j = t & 511, half = t >> 9;
      const float* wp = Wfold + (size_t)(half*128)*512 + j;
      const float* iv = hr + half*128;
      float a0=0.f, a1=0.f, a2=0.f, a3=0.f;
      #pragma unroll 4
      for (int i = 0; i < 128; i += 4) {
        a0 += iv[i]   * wp[(i)  *512];
        a1 += iv[i+1] * wp[(i+1)*512];
        a2 += iv[i+2] * wp[(i+2)*512];
        a3 += iv[i+3] * wp[(i+3)*512];
      }
      pbuf[t] = a0 + a1 + a2 + a3;
    }
    __syncthreads();
    if (t < 128) {
      float gi = pbuf[t]     + pbuf[512+t] + bs_ih[t]     + bs_hh[t];
      float gf = pbuf[128+t] + pbuf[640+t] + bs_ih[128+t] + bs_hh[128+t];
      float gg = pbuf[256+t] + pbuf[768+t] + bs_ih[256+t] + bs_hh[256+t];
      float go = pbuf[384+t] + pbuf[896+t] + bs_ih[384+t] + bs_hh[384+t];
      float ci = sigm(gf) * cbuf[t] + sigm(gi) * tanhf(gg);
      cbuf[t] = ci;
      hr[t] = sigm(go) * tanhf(ci);
    }
    __syncthreads();
  }
  if (t < 256) qpool[g*256 + t] = hr[t];
}

// ======== yhat edge-major + column sums ========
__device__ __forceinline__ float yval(const float* __restrict__ feat,
                                      const float* __restrict__ qpool,
                                      int n0, int n1, int cb, int j) {
  if (j < 128)      return 0.5f*(feat[n0*128+j] + feat[n1*128+j]);
  else if (j < 256) { int jj=j-128; return feat[n0*128+jj]*feat[n1*128+jj]; }
  else if (j < 384) { int jj=j-256; float d=feat[n0*128+jj]-feat[n1*128+jj]; return d*d; }
  else              return qpool[cb*256 + (j-384)];
}

__global__ __launch_bounds__(256) void ys_k(const float* __restrict__ feat,
    const int* __restrict__ ei3, const int* __restrict__ batch,
    const float* __restrict__ qpool,
    float* __restrict__ yhat, float* __restrict__ ysum, float* __restrict__ ysq) {
  int t = threadIdx.x;
  int e0 = blockIdx.x * 8;
  float s0=0,q0=0,s1=0,q1=0,s2=0,q2=0;
  for (int ee = 0; ee < 8; ee++) {
    int e = e0 + ee;
    int n0 = ei3[e], n1 = ei3[N_E3 + e];
    int cb = batch[n0];
    float v0 = yval(feat, qpool, n0, n1, cb, t);
    yhat[(size_t)e*640 + t] = v0; s0 += v0; q0 += v0*v0;
    float v1 = yval(feat, qpool, n0, n1, cb, t + 256);
    yhat[(size_t)e*640 + t + 256] = v1; s1 += v1; q1 += v1*v1;
    if (t < 128) {
      float v2 = yval(feat, qpool, n0, n1, cb, t + 512);
      yhat[(size_t)e*640 + t + 512] = v2; s2 += v2; q2 += v2*v2;
    }
  }
  atomicAdd(&ysum[t], s0);        atomicAdd(&ysq[t], q0);
  atomicAdd(&ysum[t + 256], s1);  atomicAdd(&ysq[t + 256], q1);
  if (t < 128) { atomicAdd(&ysum[t + 512], s2); atomicAdd(&ysq[t + 512], q2); }
}

__global__ void final_k(const float* __restrict__ yhat,
                        const float* __restrict__ ysum, const float* __restrict__ ysq,
                        const float* __restrict__ g, const float* __restrict__ b,
                        const float* __restrict__ ea3,
                        const float* __restrict__ Ww, const float* __restrict__ Wb,
                        float* __restrict__ out) {
  int e = blockIdx.x, t = threadIdx.x;
  __shared__ float red[128];
  const float invE = 1.f / (float)N_E3;
  float av[8];
  #pragma unroll
  for (int k = 0; k < 8; k++) av[k] = ea3[e*8 + k];
  float acc = 0.f;
  for (int j = t; j < 640; j += 128) {
    float m = ysum[j] * invE;
    float v = ysq[j] * invE - m*m;
    float yn = (yhat[(size_t)e*640 + j] - m) * rsqrtf(v + BN_EPS) * g[j] + b[j];
    float wj = 0.f;
    #pragma unroll
    for (int k = 0; k < 8; k++) wj += av[k] * Ww[k*640 + j];
    acc += yn * wj;
  }
  red[t] = acc; __syncthreads();
  for (int w = 64; w > 0; w >>= 1) {
    if (t < w) red[t] += red[t+w];
    __syncthreads();
  }
  if (t == 0) {
    float bb = 0.f;
    #pragma unroll
    for (int k = 0; k < 8; k++) bb += av[k] * Wb[k];
    out[e] = red[0] + bb;
  }
}

extern "C" void kernel_launch(void* const* d_in, const int* in_sizes, int n_in,
                              void* d_out, int out_size, void* d_ws, size_t ws_size,
                              hipStream_t stream) {
  const float* x      = (const float*)d_in[0];
  const int*   ei     = (const int*)  d_in[1];
  const float* eattr  = (const float*)d_in[2];
  const int*   ei3    = (const int*)  d_in[3];
  const float* ea3    = (const float*)d_in[4];
  const int*   batch  = (const int*)  d_in[5];
  const float* bnx_g  = (const float*)d_in[6];
  const float* bnx_b  = (const float*)d_in[7];
  const float* Wn     = (const float*)d_in[8];
  const float* bnode  = (const float*)d_in[9];
  const float* We     = (const float*)d_in[10];
  const float* be     = (const float*)d_in[11];
  const float* Wnn1   = (const float*)d_in[12];
  const float* bias1  = (const float*)d_in[13];
  const float* Wih1   = (const float*)d_in[14];
  const float* Whh1   = (const float*)d_in[15];
  const float* bih1   = (const float*)d_in[16];
  const float* bhh1   = (const float*)d_in[17];
  const float* bnc_g  = (const float*)d_in[18];
  const float* bnc_b  = (const float*)d_in[19];
  const float* Wc1    = (const float*)d_in[20];
  const float* bc1    = (const float*)d_in[21];
  const float* Wc2    = (const float*)d_in[22];
  const float* bc2    = (const float*)d_in[23];
  const float* Wnn2   = (const float*)d_in[24];
  const float* bias2  = (const float*)d_in[25];
  const float* Wih2   = (const float*)d_in[26];
  const float* Whh2   = (const float*)d_in[27];
  const float* bih2   = (const float*)d_in[28];
  const float* bhh2   = (const float*)d_in[29];
  const float* Ws_ih  = (const float*)d_in[30];
  const float* Ws_hh  = (const float*)d_in[31];
  const float* bs_ih  = (const float*)d_in[32];
  const float* bs_hh  = (const float*)d_in[33];
  const float* bno_g  = (const float*)d_in[34];
  const float* bno_b  = (const float*)d_in[35];
  const float* Ww     = (const float*)d_in[36];
  const float* Wb     = (const float*)d_in[37];
  float* out = (float*)d_out;

  // workspace carve-up
  float* W = (float*)d_ws;
  size_t off = 0;
  float* Wfold  = W + off; off += 131072;
  float* ea12   = W + off; off += (size_t)N_EDGES * 12;
  float* nodeA  = W + off; off += (size_t)N_NODES * 64;
  float* nodeA2 = W + off; off += (size_t)N_NODES * 64;
  float* sA1    = W + off; off += (size_t)N_NODES * 64;
  float* sA2    = W + off; off += (size_t)N_NODES * 64;
  float* sB1    = W + off; off += (size_t)N_NODES * 128;
  float* sB2    = W + off; off += (size_t)N_NODES * 128;
  float* cnt1   = W + off; off += (size_t)N_NODES;
  float* cnt2   = W + off; off += (size_t)N_NODES;
  float* nodeB  = W + off; off += (size_t)N_NODES * 128;
  float* nodeB2 = W + off; off += (size_t)N_NODES * 128;
  float* qpool  = W + off; off += (size_t)NGRAPH * 256;
  float* yhat   = W + off; off += (size_t)N_E3 * 640;
  float* mean   = W + off; off += 640;
  float* var    = W + off; off += 640;
  float* bns1   = W + off; off += 128;
  float* bns2   = W + off; off += 128;
  float* ysum   = W + off; off += 640;
  float* ysq    = W + off; off += 640;
  f16* F = (f16*)(W + off);
  size_t foff = 0;
  f16* Wz1h  = F + foff; foff += 49152;
  f16* Wih1h = F + foff; foff += 12288;
  f16* Whh1h = F + foff; foff += 12288;
  f16* Wc1Th = F + foff; foff += 8192;
  f16* Wc2Th = F + foff; foff += 16384;
  f16* W2fh  = F + foff; foff += 131072;
  f16* Wih2h = F + foff; foff += 49152;
  f16* Whh2h = F + foff; foff += 49152;
  (void)foff; (void)ws_size; (void)in_sizes; (void)n_in; (void)out_size;

  // 1. pack v3 + 2. embeds
  pack_k<<<282, 256, 0, stream>>>(Wnn1, Wih1, Whh1, Wc1, Wc2, Wnn2, Wih2, Whh2, Ws_ih, Ws_hh, x,
                                  Wz1h, Wih1h, Whh1h, Wc1Th, Wc2Th, W2fh, Wih2h, Whh2h,
                                  Wfold, cnt1, cnt2, bns1, bns2, ysum, ysq, mean, var);
  embed_k<<<2896, 256, 0, stream>>>(x, mean, var, bnx_g, bnx_b, Wn, bnode, nodeA,
                                    eattr, We, be, ea12, ei, ei3, cnt1, cnt2, sA1);

  // 3-6. layer-1 x2
  conv1f_k<<<512, 256, 0, stream>>>(nodeA, ei, ea12, Wz1h, sA1);
  gruf_k<6,0,1><<<512 + 16, 256, 0, stream>>>(sA1, cnt1, bias1, Wih1h, Whh1h, bih1, bhh1,
                                              nodeA, nodeA2, nullptr, nullptr,
                                              512, sA2, N_NODES*64);
  conv1f_k<<<512, 256, 0, stream>>>(nodeA2, ei, ea12, Wz1h, sA2);
  gruf_k<6,1,1><<<512 + 16, 256, 0, stream>>>(sA2, cnt1, bias1, Wih1h, Whh1h, bih1, bhh1,
                                              nodeA2, nodeA, bns1, bns2,
                                              512, sB1, N_NODES*128);

  // 7. fused BN + FC1 + FC2 (+zero sB2)
  fcf_k<<<512 + 16, 128, 0, stream>>>(nodeA, Wc1Th, bc1, Wc2Th, bc2,
                                      bns1, bns2, bnc_g, bnc_b, nodeB,
                                      512, sB2, N_NODES*128);

  // 8-11. layer-2 x2
  conv2f_k<<<256, 512, 0, stream>>>(nodeB, ei3, ea3, W2fh, sB1);
  gruf_k<7,0,2><<<512, 256, 0, stream>>>(sB1, cnt2, bias2, Wih2h, Whh2h, bih2, bhh2,
                                         nodeB, nodeB2, nullptr, nullptr,
                                         512, nullptr, 0);
  conv2f_k<<<256, 512, 0, stream>>>(nodeB2, ei3, ea3, W2fh, sB2);
  gruf_k<7,0,2><<<512, 256, 0, stream>>>(sB2, cnt2, bias2, Wih2h, Whh2h, bih2, bhh2,
                                         nodeB2, nodeB, nullptr, nullptr,
                                         512, nullptr, 0);

  // 12. set2set
  set2set_k<<<NGRAPH, 1024, 0, stream>>>(nodeB, Wfold, bs_ih, bs_hh, qpool);

  // 13-14. yhat + sums, weighted sum
  ys_k<<<128, 256, 0, stream>>>(nodeB, ei3, batch, qpool, yhat, ysum, ysq);
  final_k<<<N_E3, 128, 0, stream>>>(yhat, ysum, ysq, bno_g, bno_b, ea3, Ww, Wb, out);
}